// Round 2
// baseline (336.754 us; speedup 1.0000x reference)
//
#include <hip/hip_runtime.h>

#define N_NODES 16384
#define N_EDGES 262144
#define EP (N_EDGES + N_NODES)   // with self-loops
#define HID 128
#define ENC 768
#define ENCP (ENC/2)             // 384 bf16-pairs per row
#define NEG 0.2f
#define EPSV 1e-5f

__device__ __forceinline__ float wave_sum(float v){
  #pragma unroll
  for(int m=32;m>=1;m>>=1) v += __shfl_xor(v, m, 64);
  return v;
}
__device__ __forceinline__ float lrelu(float v){ return v > 0.f ? v : NEG*v; }
__device__ __forceinline__ unsigned bf16rtne(float f){
  const unsigned u = __float_as_uint(f);
  return (u + 0x7fffu + ((u>>16)&1u)) >> 16;
}
__device__ __forceinline__ unsigned pack2(float a, float b){
  return bf16rtne(a) | (bf16rtne(b) << 16);
}

// ---- input transforms for layer 1: xl1 = x@W1l+b1l, xr1 = x@W1r+b1r ----
__global__ __launch_bounds__(256) void lin1_kernel(
    const float* __restrict__ x,
    const float* __restrict__ Wl, const float* __restrict__ bl,
    const float* __restrict__ Wr, const float* __restrict__ br,
    float* __restrict__ xl1, float* __restrict__ xr1){
  const int i = blockIdx.x*256 + threadIdx.x;        // exactly N*HID threads
  const int n = i >> 7, c = i & 127;
  const float x0 = x[n*3], x1 = x[n*3+1], x2 = x[n*3+2];
  xl1[i] = x0*Wl[c] + x1*Wl[HID+c] + x2*Wl[2*HID+c] + bl[c];
  xr1[i] = x0*Wr[c] + x1*Wr[HID+c] + x2*Wr[2*HID+c] + br[c];
}

// ---- CSR build: histogram of dst ----
__global__ __launch_bounds__(256) void hist_kernel(
    const int* __restrict__ ei, int* __restrict__ hist){
  const int i = blockIdx.x*256 + threadIdx.x;        // exactly EP threads
  const int dst = (i < N_EDGES) ? ei[N_EDGES + i] : (i - N_EDGES);
  atomicAdd(&hist[dst], 1);
}

// ---- single-block exclusive scan over N=16384 (1024 thr x 16 items) ----
__global__ __launch_bounds__(1024) void scan_kernel(
    const int* __restrict__ hist, int* __restrict__ rowstart){
  __shared__ int sums[1024];
  const int t = threadIdx.x;
  const int base = t*16;
  int loc[16];
  int s = 0;
  #pragma unroll
  for(int i=0;i<16;i++){ loc[i] = s; s += hist[base+i]; }
  sums[t] = s;
  __syncthreads();
  for(int off=1; off<1024; off<<=1){
    int v = 0;
    if(t >= off) v = sums[t-off];
    __syncthreads();
    if(t >= off) sums[t] += v;
    __syncthreads();
  }
  const int prev = (t==0) ? 0 : sums[t-1];
  #pragma unroll
  for(int i=0;i<16;i++) rowstart[base+i] = prev + loc[i];
  if(t == 1023) rowstart[N_NODES] = EP;
}

// ---- CSR build: scatter src ids into dst-sorted order ----
__global__ __launch_bounds__(256) void scatter_kernel(
    const int* __restrict__ ei, const int* __restrict__ rowstart,
    int* __restrict__ cursor, int* __restrict__ ssrc){
  const int i = blockIdx.x*256 + threadIdx.x;        // exactly EP threads
  const int src = (i < N_EDGES) ? ei[i]           : (i - N_EDGES);
  const int dst = (i < N_EDGES) ? ei[N_EDGES + i] : (i - N_EDGES);
  const int pos = rowstart[dst] + atomicAdd(&cursor[dst], 1);
  ssrc[pos] = src;
}

// ---- GAT layer 1 per-node: score+softmax+aggregate+bias+LN+ELU, 1 wave/node ----
__global__ __launch_bounds__(256) void node1_kernel(
    const float* __restrict__ xl1, const float* __restrict__ xr1,
    const float* __restrict__ att1, const float* __restrict__ bias1,
    const float* __restrict__ g1, const float* __restrict__ b1,
    const int* __restrict__ rowstart, const int* __restrict__ ssrc,
    float* __restrict__ h1){
  const int lane = threadIdx.x & 63;
  const int n = blockIdx.x*4 + (threadIdx.x >> 6);
  const int c0 = lane, c1 = lane + 64;
  const float xra = xr1[n*HID+c0], xrb = xr1[n*HID+c1];
  const float aa = att1[c0], ab = att1[c1];
  float acc0 = 0.f, acc1 = 0.f, denom = 0.f;
  const int p0 = rowstart[n], p1 = rowstart[n+1];
  for(int p=p0; p<p1; ++p){
    const int s = ssrc[p];
    const float v0 = xl1[s*HID+c0], v1 = xl1[s*HID+c1];
    const float e = wave_sum(lrelu(v0+xra)*aa + lrelu(v1+xrb)*ab);
    const float w = expf(e);              // max-shift cancels in alpha; |e| small
    denom += w; acc0 += w*v0; acc1 += w*v1;
  }
  const float inv = 1.f/denom;
  const float y0 = acc0*inv + bias1[c0];
  const float y1 = acc1*inv + bias1[c1];
  const float mu  = wave_sum(y0+y1) * (1.f/HID);
  const float d0 = y0-mu, d1 = y1-mu;
  const float var = wave_sum(d0*d0 + d1*d1) * (1.f/HID);
  const float r = rsqrtf(var + EPSV);
  float z0 = d0*r*g1[c0] + b1[c0];
  float z1 = d1*r*g1[c1] + b1[c1];
  z0 = z0 > 0.f ? z0 : expm1f(z0);        // ELU(alpha=1)
  z1 = z1 > 0.f ? z1 : expm1f(z1);
  h1[n*HID+c0] = z0; h1[n*HID+c1] = z1;
}

// ---- layer-2 transforms in bf16 (scores only need low precision):
//      xl2b = bf16(h1@W2l+b2l), xr2b = bf16(h1@W2r+b2r), packed 2/word ----
#define TM2 16
__global__ __launch_bounds__(384) void lin2b_kernel(
    const float* __restrict__ h1,
    const float* __restrict__ Wl, const float* __restrict__ bl,
    const float* __restrict__ Wr, const float* __restrict__ br,
    unsigned* __restrict__ xl2b, unsigned* __restrict__ xr2b){
  __shared__ float hs[TM2][HID];
  const int t = threadIdx.x;            // 0..383 : owns column pair (2t, 2t+1)
  const int nb = blockIdx.x * TM2;
  for(int i=t; i<TM2*HID; i+=384) hs[i>>7][i&127] = h1[nb*HID + i];
  __syncthreads();
  float al[TM2][2] = {}; float ar[TM2][2] = {};
  const float2* Wl2 = (const float2*)Wl;
  const float2* Wr2 = (const float2*)Wr;
  for(int k=0; k<HID; ++k){
    const float2 wl = Wl2[k*ENCP + t];
    const float2 wr = Wr2[k*ENCP + t];
    #pragma unroll
    for(int nn=0; nn<TM2; ++nn){
      const float hv = hs[nn][k];
      al[nn][0] += hv*wl.x; al[nn][1] += hv*wl.y;
      ar[nn][0] += hv*wr.x; ar[nn][1] += hv*wr.y;
    }
  }
  const float2 blv = ((const float2*)bl)[t];
  const float2 brv = ((const float2*)br)[t];
  #pragma unroll
  for(int nn=0; nn<TM2; ++nn){
    const size_t row = (size_t)(nb+nn)*ENCP;
    xl2b[row+t] = pack2(al[nn][0]+blv.x, al[nn][1]+blv.y);
    xr2b[row+t] = pack2(ar[nn][0]+brv.x, ar[nn][1]+brv.y);
  }
}

// ---- GAT layer 2: scores from bf16 xl2b/xr2b, aggregate 128-dim h1
//      (sum(alpha)=1 lets the W2l matmul commute out of the aggregation) ----
__global__ __launch_bounds__(256) void node2b_kernel(
    const unsigned* __restrict__ xl2b, const unsigned* __restrict__ xr2b,
    const float* __restrict__ att2, const float* __restrict__ h1,
    const int* __restrict__ rowstart, const int* __restrict__ ssrc,
    float* __restrict__ agg){
  const int lane = threadIdx.x & 63;
  const int n = blockIdx.x*4 + (threadIdx.x >> 6);
  unsigned xrp[6]; float2 at[6];
  const unsigned* xrrow = xr2b + (size_t)n*ENCP;
  const float2* att22 = (const float2*)att2;
  #pragma unroll
  for(int j=0;j<6;j++){
    const int pidx = lane + 64*j;
    xrp[j] = xrrow[pidx]; at[j] = att22[pidx];
  }
  float denom = 0.f, acc0 = 0.f, acc1 = 0.f;
  const int p0 = rowstart[n], p1 = rowstart[n+1];
  for(int p=p0; p<p1; ++p){
    const int s = ssrc[p];
    const unsigned* xlrow = xl2b + (size_t)s*ENCP;
    unsigned v[6];
    #pragma unroll
    for(int j=0;j<6;j++) v[j] = xlrow[lane + 64*j];
    const float hv0 = h1[s*HID+lane], hv1 = h1[s*HID+lane+64];
    float partial = 0.f;
    #pragma unroll
    for(int j=0;j<6;j++){
      const float vx = __uint_as_float(v[j] << 16);
      const float vy = __uint_as_float(v[j] & 0xffff0000u);
      const float rx = __uint_as_float(xrp[j] << 16);
      const float ry = __uint_as_float(xrp[j] & 0xffff0000u);
      partial += lrelu(vx+rx)*at[j].x + lrelu(vy+ry)*at[j].y;
    }
    const float e = wave_sum(partial);
    const float w = expf(e);
    denom += w; acc0 += w*hv0; acc1 += w*hv1;
  }
  const float inv = 1.f/denom;
  agg[n*HID+lane]    = acc0*inv;
  agg[n*HID+lane+64] = acc1*inv;
}

// ---- final: out = LN( agg@W2l + b2l + bias2 + (x@Wfc+bfc) ) ----
#define TM3 16
__global__ __launch_bounds__(256) void gemm3_kernel(
    const float* __restrict__ agg, const float* __restrict__ Wl,
    const float* __restrict__ b2l, const float* __restrict__ bias2,
    const float* __restrict__ x, const float* __restrict__ Wfc,
    const float* __restrict__ bfc,
    const float* __restrict__ gn, const float* __restrict__ bn,
    float* __restrict__ out){
  __shared__ float hs[TM3][HID];
  __shared__ float xs[TM3][3];
  __shared__ float red[2][TM3][4];
  const int t = threadIdx.x;
  const int nb = blockIdx.x * TM3;
  for(int i=t; i<TM3*HID; i+=256) hs[i>>7][i&127] = agg[nb*HID + i];
  if(t < TM3*3) xs[t/3][t%3] = x[nb*3 + t];
  __syncthreads();
  float acc[TM3][3] = {};
  const int c0 = t, c1 = t+256, c2 = t+512;
  for(int k=0; k<HID; ++k){
    const float w0 = Wl[k*ENC+c0], w1 = Wl[k*ENC+c1], w2 = Wl[k*ENC+c2];
    #pragma unroll
    for(int nn=0; nn<TM3; ++nn){
      const float hv = hs[nn][k];
      acc[nn][0] += hv*w0; acc[nn][1] += hv*w1; acc[nn][2] += hv*w2;
    }
  }
  const float add0 = b2l[c0]+bias2[c0], add1 = b2l[c1]+bias2[c1], add2 = b2l[c2]+bias2[c2];
  const float f00=Wfc[c0], f01=Wfc[ENC+c0], f02=Wfc[2*ENC+c0], bf0=bfc[c0];
  const float f10=Wfc[c1], f11=Wfc[ENC+c1], f12=Wfc[2*ENC+c1], bf1=bfc[c1];
  const float f20=Wfc[c2], f21=Wfc[ENC+c2], f22=Wfc[2*ENC+c2], bf2=bfc[c2];
  const int wid = t >> 6, lane = t & 63;
  #pragma unroll
  for(int nn=0; nn<TM3; ++nn){
    const float x0 = xs[nn][0], x1 = xs[nn][1], x2 = xs[nn][2];
    acc[nn][0] += add0 + x0*f00 + x1*f01 + x2*f02 + bf0;
    acc[nn][1] += add1 + x0*f10 + x1*f11 + x2*f12 + bf1;
    acc[nn][2] += add2 + x0*f20 + x1*f21 + x2*f22 + bf2;
  }
  #pragma unroll
  for(int nn=0; nn<TM3; ++nn){
    float s = acc[nn][0] + acc[nn][1] + acc[nn][2];
    float q = acc[nn][0]*acc[nn][0] + acc[nn][1]*acc[nn][1] + acc[nn][2]*acc[nn][2];
    s = wave_sum(s); q = wave_sum(q);
    if(lane == 0){ red[0][nn][wid] = s; red[1][nn][wid] = q; }
  }
  __syncthreads();
  const float gv0=gn[c0], gv1=gn[c1], gv2=gn[c2];
  const float bv0=bn[c0], bv1=bn[c1], bv2=bn[c2];
  #pragma unroll
  for(int nn=0; nn<TM3; ++nn){
    const float sum = red[0][nn][0]+red[0][nn][1]+red[0][nn][2]+red[0][nn][3];
    const float sq  = red[1][nn][0]+red[1][nn][1]+red[1][nn][2]+red[1][nn][3];
    const float mu  = sum * (1.f/ENC);
    const float var = sq * (1.f/ENC) - mu*mu;
    const float r = rsqrtf(var + EPSV);
    float* orow = out + (size_t)(nb+nn)*ENC;
    orow[c0] = (acc[nn][0]-mu)*r*gv0 + bv0;
    orow[c1] = (acc[nn][1]-mu)*r*gv1 + bv1;
    orow[c2] = (acc[nn][2]-mu)*r*gv2 + bv2;
  }
}

extern "C" void kernel_launch(void* const* d_in, const int* in_sizes, int n_in,
                              void* d_out, int out_size, void* d_ws, size_t ws_size,
                              hipStream_t stream) {
  const float* x    = (const float*)d_in[0];
  const int*   ei   = (const int*)  d_in[1];
  const float* Wfc  = (const float*)d_in[2];
  const float* bfc  = (const float*)d_in[3];
  const float* W1l  = (const float*)d_in[4];
  const float* b1l  = (const float*)d_in[5];
  const float* W1r  = (const float*)d_in[6];
  const float* b1r  = (const float*)d_in[7];
  const float* att1 = (const float*)d_in[8];
  const float* bias1= (const float*)d_in[9];
  const float* g1   = (const float*)d_in[10];
  const float* bb1  = (const float*)d_in[11];
  const float* W2l  = (const float*)d_in[12];
  const float* b2l  = (const float*)d_in[13];
  const float* W2r  = (const float*)d_in[14];
  const float* b2r  = (const float*)d_in[15];
  const float* att2 = (const float*)d_in[16];
  const float* bias2= (const float*)d_in[17];
  const float* gn   = (const float*)d_in[18];
  const float* bn   = (const float*)d_in[19];
  float* out = (float*)d_out;

  char* w = (char*)d_ws;
  auto alloc = [&](size_t bytes){ void* p = (void*)w; w += (bytes + 255) & ~(size_t)255; return p; };
  int*      hist     = (int*)     alloc((size_t)N_NODES*4);   // contiguous with cursor
  int*      cursor   = (int*)     alloc((size_t)N_NODES*4);
  int*      rowstart = (int*)     alloc((size_t)(N_NODES+1)*4);
  int*      ssrc     = (int*)     alloc((size_t)EP*4);
  float*    xl1      = (float*)   alloc((size_t)N_NODES*HID*4);
  float*    xr1      = (float*)   alloc((size_t)N_NODES*HID*4);
  float*    h1       = (float*)   alloc((size_t)N_NODES*HID*4);
  float*    agg      = (float*)   alloc((size_t)N_NODES*HID*4);
  unsigned* xl2b     = (unsigned*)alloc((size_t)N_NODES*ENCP*4);
  unsigned* xr2b     = (unsigned*)alloc((size_t)N_NODES*ENCP*4);

  hipMemsetAsync(hist, 0, (size_t)N_NODES*8, stream);   // hist + cursor

  lin1_kernel<<<N_NODES*HID/256, 256, 0, stream>>>(x, W1l, b1l, W1r, b1r, xl1, xr1);
  hist_kernel<<<EP/256, 256, 0, stream>>>(ei, hist);
  scan_kernel<<<1, 1024, 0, stream>>>(hist, rowstart);
  scatter_kernel<<<EP/256, 256, 0, stream>>>(ei, rowstart, cursor, ssrc);
  node1_kernel<<<N_NODES/4, 256, 0, stream>>>(xl1, xr1, att1, bias1, g1, bb1,
                                              rowstart, ssrc, h1);
  lin2b_kernel<<<N_NODES/TM2, 384, 0, stream>>>(h1, W2l, b2l, W2r, b2r, xl2b, xr2b);
  node2b_kernel<<<N_NODES/4, 256, 0, stream>>>(xl2b, xr2b, att2, h1,
                                               rowstart, ssrc, agg);
  gemm3_kernel<<<N_NODES/TM3, 256, 0, stream>>>(agg, W2l, b2l, bias2,
                                                x, Wfc, bfc, gn, bn, out);
}

// Round 3
// 251.502 us; speedup vs baseline: 1.3390x; 1.3390x over previous
//
#include <hip/hip_runtime.h>

#define N_NODES 16384
#define N_EDGES 262144
#define EP (N_EDGES + N_NODES)   // with self-loops
#define HID 128
#define ENC 768
#define ENCP (ENC/2)             // 384 bf16-pairs per row
#define NEG 0.2f
#define EPSV 1e-5f

typedef unsigned short u16;
using f32x4  = __attribute__((ext_vector_type(4))) float;
using bf16x8 = __attribute__((ext_vector_type(8))) short;

__device__ __forceinline__ float wave_sum(float v){
  #pragma unroll
  for(int m=32;m>=1;m>>=1) v += __shfl_xor(v, m, 64);
  return v;
}
__device__ __forceinline__ float lrelu(float v){ return v > 0.f ? v : NEG*v; }
__device__ __forceinline__ unsigned bf16rtne(float f){
  const unsigned u = __float_as_uint(f);
  return (u + 0x7fffu + ((u>>16)&1u)) >> 16;
}
__device__ __forceinline__ unsigned pack2(float a, float b){
  return bf16rtne(a) | (bf16rtne(b) << 16);
}
__device__ __forceinline__ float bf2f(u16 h){ return __uint_as_float(((unsigned)h) << 16); }

// ---- input transforms for layer 1: xl1 = x@W1l+b1l, xr1 = x@W1r+b1r ----
__global__ __launch_bounds__(256) void lin1_kernel(
    const float* __restrict__ x,
    const float* __restrict__ Wl, const float* __restrict__ bl,
    const float* __restrict__ Wr, const float* __restrict__ br,
    float* __restrict__ xl1, float* __restrict__ xr1){
  const int i = blockIdx.x*256 + threadIdx.x;        // exactly N*HID threads
  const int n = i >> 7, c = i & 127;
  const float x0 = x[n*3], x1 = x[n*3+1], x2 = x[n*3+2];
  xl1[i] = x0*Wl[c] + x1*Wl[HID+c] + x2*Wl[2*HID+c] + bl[c];
  xr1[i] = x0*Wr[c] + x1*Wr[HID+c] + x2*Wr[2*HID+c] + br[c];
}

// ---- W2l/W2r -> transposed bf16 Wtb[1536][128] ----
__global__ __launch_bounds__(256) void wprep_kernel(
    const float* __restrict__ W2l, const float* __restrict__ W2r,
    u16* __restrict__ Wtb){
  const int idx = blockIdx.x*256 + threadIdx.x;      // 1536*128 threads
  const int n = idx >> 7, k = idx & 127;
  const float v = (n < ENC) ? W2l[k*ENC + n] : W2r[k*ENC + (n-ENC)];
  Wtb[idx] = (u16)bf16rtne(v);
}

// ---- CSR build: histogram of dst ----
__global__ __launch_bounds__(256) void hist_kernel(
    const int* __restrict__ ei, int* __restrict__ hist){
  const int i = blockIdx.x*256 + threadIdx.x;        // exactly EP threads
  const int dst = (i < N_EDGES) ? ei[N_EDGES + i] : (i - N_EDGES);
  atomicAdd(&hist[dst], 1);
}

// ---- single-block exclusive scan over N=16384 (1024 thr x 16 items) ----
__global__ __launch_bounds__(1024) void scan_kernel(
    const int* __restrict__ hist, int* __restrict__ rowstart){
  __shared__ int sums[1024];
  const int t = threadIdx.x;
  const int base = t*16;
  int loc[16];
  int s = 0;
  #pragma unroll
  for(int i=0;i<16;i++){ loc[i] = s; s += hist[base+i]; }
  sums[t] = s;
  __syncthreads();
  for(int off=1; off<1024; off<<=1){
    int v = 0;
    if(t >= off) v = sums[t-off];
    __syncthreads();
    if(t >= off) sums[t] += v;
    __syncthreads();
  }
  const int prev = (t==0) ? 0 : sums[t-1];
  #pragma unroll
  for(int i=0;i<16;i++) rowstart[base+i] = prev + loc[i];
  if(t == 1023) rowstart[N_NODES] = EP;
}

// ---- CSR build: scatter src ids into dst-sorted order ----
__global__ __launch_bounds__(256) void scatter_kernel(
    const int* __restrict__ ei, const int* __restrict__ rowstart,
    int* __restrict__ cursor, int* __restrict__ ssrc){
  const int i = blockIdx.x*256 + threadIdx.x;        // exactly EP threads
  const int src = (i < N_EDGES) ? ei[i]           : (i - N_EDGES);
  const int dst = (i < N_EDGES) ? ei[N_EDGES + i] : (i - N_EDGES);
  const int pos = rowstart[dst] + atomicAdd(&cursor[dst], 1);
  ssrc[pos] = src;
}

// ---- GAT layer 1 per-node: score+softmax+aggregate+bias+LN+ELU -> bf16 h1b ----
__global__ __launch_bounds__(256) void node1_kernel(
    const float* __restrict__ xl1, const float* __restrict__ xr1,
    const float* __restrict__ att1, const float* __restrict__ bias1,
    const float* __restrict__ g1, const float* __restrict__ b1,
    const int* __restrict__ rowstart, const int* __restrict__ ssrc,
    u16* __restrict__ h1b){
  const int lane = threadIdx.x & 63;
  const int n = blockIdx.x*4 + (threadIdx.x >> 6);
  const int c0 = lane, c1 = lane + 64;
  const float xra = xr1[n*HID+c0], xrb = xr1[n*HID+c1];
  const float aa = att1[c0], ab = att1[c1];
  float acc0 = 0.f, acc1 = 0.f, denom = 0.f;
  const int p0 = rowstart[n], p1 = rowstart[n+1];
  for(int p=p0; p<p1; ++p){
    const int s = ssrc[p];
    const float v0 = xl1[s*HID+c0], v1 = xl1[s*HID+c1];
    const float e = wave_sum(lrelu(v0+xra)*aa + lrelu(v1+xrb)*ab);
    const float w = expf(e);              // max-shift cancels in alpha; |e| small
    denom += w; acc0 += w*v0; acc1 += w*v1;
  }
  const float inv = 1.f/denom;
  const float y0 = acc0*inv + bias1[c0];
  const float y1 = acc1*inv + bias1[c1];
  const float mu  = wave_sum(y0+y1) * (1.f/HID);
  const float d0 = y0-mu, d1 = y1-mu;
  const float var = wave_sum(d0*d0 + d1*d1) * (1.f/HID);
  const float r = rsqrtf(var + EPSV);
  float z0 = d0*r*g1[c0] + b1[c0];
  float z1 = d1*r*g1[c1] + b1[c1];
  z0 = z0 > 0.f ? z0 : expm1f(z0);        // ELU(alpha=1)
  z1 = z1 > 0.f ? z1 : expm1f(z1);
  h1b[n*HID+c0] = (u16)bf16rtne(z0);
  h1b[n*HID+c1] = (u16)bf16rtne(z1);
}

// ---- MFMA GEMM: [xl2b|xr2b](16384 x 1536) = h1b(16384x128) @ Wtb^T + bias ----
// block = 4 waves, tile 128x128; wave computes 32 rows x 128 cols.
// Only the HW-verified C/D layout is relied upon; A/B use a consistent
// (group,elem)->k bijection (k = g*8+i), valid for any HW interleave.
#define LBM 128
#define LBN 128
__global__ __launch_bounds__(256) void mfma_lin2_kernel(
    const u16* __restrict__ h1b, const u16* __restrict__ Wtb,
    const float* __restrict__ b2l, const float* __restrict__ b2r,
    u16* __restrict__ xl2u, u16* __restrict__ xr2u){
  __shared__ __align__(16) u16 As[LBM*128];   // 32 KB, swizzled rows of 256B
  __shared__ __align__(16) u16 Bs[LBN*128];   // 32 KB
  const int t = threadIdx.x;
  const int mb = blockIdx.x * LBM;
  const int nb = blockIdx.y * LBN;
  const int rr = t >> 4, cc = t & 15;
  #pragma unroll
  for(int it=0; it<8; ++it){
    const int row = it*16 + rr;
    const uint4 va = *(const uint4*)(h1b + (size_t)(mb+row)*128 + cc*8);
    *(uint4*)((char*)As + row*256 + ((cc*16) ^ ((row&7)<<4))) = va;
    const uint4 vb = *(const uint4*)(Wtb + (size_t)(nb+row)*128 + cc*8);
    *(uint4*)((char*)Bs + row*256 + ((cc*16) ^ ((row&7)<<4))) = vb;
  }
  __syncthreads();
  const int w = t >> 6, lane = t & 63;
  const int l15 = lane & 15, g = lane >> 4;
  f32x4 acc0[8], acc1[8];
  #pragma unroll
  for(int j=0;j<8;j++){ acc0[j]=(f32x4){0,0,0,0}; acc1[j]=(f32x4){0,0,0,0}; }
  const int ar0 = w*32 + l15, ar1 = w*32 + 16 + l15;
  #pragma unroll
  for(int ks=0; ks<4; ++ks){
    const int kb = ks*64 + g*16;              // byte offset of this lane's 8 bf16
    const bf16x8 a0 = *(const bf16x8*)((const char*)As + ar0*256 + (kb ^ ((ar0&7)<<4)));
    const bf16x8 a1 = *(const bf16x8*)((const char*)As + ar1*256 + (kb ^ ((ar1&7)<<4)));
    #pragma unroll
    for(int j=0;j<8;j++){
      const int br = j*16 + l15;
      const bf16x8 b = *(const bf16x8*)((const char*)Bs + br*256 + (kb ^ ((br&7)<<4)));
      acc0[j] = __builtin_amdgcn_mfma_f32_16x16x32_bf16(a0, b, acc0[j], 0,0,0);
      acc1[j] = __builtin_amdgcn_mfma_f32_16x16x32_bf16(a1, b, acc1[j], 0,0,0);
    }
  }
  __syncthreads();
  // epilogue: +bias (fp32), pack bf16 into Cs (=As), then coalesced row writes
  const float* bsrc = (nb < ENC) ? (b2l + nb) : (b2r + (nb - ENC));
  float biasj[8];
  #pragma unroll
  for(int j=0;j<8;j++) biasj[j] = bsrc[j*16 + l15];
  u16* Cs = As;
  #pragma unroll
  for(int j=0;j<8;j++){
    const int coll = j*16 + l15;              // C/D: col = lane&15 (verified)
    #pragma unroll
    for(int r4=0;r4<4;r4++){
      const int row0 = w*32 + g*4 + r4;       // C/D: row = (lane>>4)*4+reg
      *(u16*)((char*)Cs + row0*256 + ((coll*2) ^ ((row0&7)<<4))) =
          (u16)bf16rtne(acc0[j][r4] + biasj[j]);
      const int row1 = row0 + 16;
      *(u16*)((char*)Cs + row1*256 + ((coll*2) ^ ((row1&7)<<4))) =
          (u16)bf16rtne(acc1[j][r4] + biasj[j]);
    }
  }
  __syncthreads();
  u16* dst0 = (nb < ENC) ? (xl2u + nb) : (xr2u + (nb - ENC));
  #pragma unroll
  for(int it=0; it<8; ++it){
    const int row = it*16 + rr;
    const uint4 v = *(const uint4*)((const char*)Cs + row*256 + ((cc*16) ^ ((row&7)<<4)));
    *(uint4*)(dst0 + (size_t)(mb+row)*ENC + cc*8) = v;
  }
}

// ---- GAT layer 2: scores from bf16 xl2b/xr2b, aggregate 128-dim bf16 h1b ----
__global__ __launch_bounds__(256) void node2b_kernel(
    const unsigned* __restrict__ xl2b, const unsigned* __restrict__ xr2b,
    const float* __restrict__ att2, const u16* __restrict__ h1b,
    const int* __restrict__ rowstart, const int* __restrict__ ssrc,
    float* __restrict__ agg){
  const int lane = threadIdx.x & 63;
  const int n = blockIdx.x*4 + (threadIdx.x >> 6);
  unsigned xrp[6]; float2 at[6];
  const unsigned* xrrow = xr2b + (size_t)n*ENCP;
  const float2* att22 = (const float2*)att2;
  #pragma unroll
  for(int j=0;j<6;j++){
    const int pidx = lane + 64*j;
    xrp[j] = xrrow[pidx]; at[j] = att22[pidx];
  }
  float denom = 0.f, acc0 = 0.f, acc1 = 0.f;
  const int p0 = rowstart[n], p1 = rowstart[n+1];
  for(int p=p0; p<p1; ++p){
    const int s = ssrc[p];
    const unsigned* xlrow = xl2b + (size_t)s*ENCP;
    unsigned v[6];
    #pragma unroll
    for(int j=0;j<6;j++) v[j] = xlrow[lane + 64*j];
    const float hv0 = bf2f(h1b[s*HID+lane]);
    const float hv1 = bf2f(h1b[s*HID+lane+64]);
    float partial = 0.f;
    #pragma unroll
    for(int j=0;j<6;j++){
      const float vx = __uint_as_float(v[j] << 16);
      const float vy = __uint_as_float(v[j] & 0xffff0000u);
      const float rx = __uint_as_float(xrp[j] << 16);
      const float ry = __uint_as_float(xrp[j] & 0xffff0000u);
      partial += lrelu(vx+rx)*at[j].x + lrelu(vy+ry)*at[j].y;
    }
    const float e = wave_sum(partial);
    const float w = expf(e);
    denom += w; acc0 += w*hv0; acc1 += w*hv1;
  }
  const float inv = 1.f/denom;
  agg[n*HID+lane]    = acc0*inv;
  agg[n*HID+lane+64] = acc1*inv;
}

// ---- final: out = LN( agg@W2l + b2l + bias2 + (x@Wfc+bfc) ) ----
#define TM3 16
__global__ __launch_bounds__(256) void gemm3_kernel(
    const float* __restrict__ agg, const float* __restrict__ Wl,
    const float* __restrict__ b2l, const float* __restrict__ bias2,
    const float* __restrict__ x, const float* __restrict__ Wfc,
    const float* __restrict__ bfc,
    const float* __restrict__ gn, const float* __restrict__ bn,
    float* __restrict__ out){
  __shared__ float hs[TM3][HID];
  __shared__ float xs[TM3][3];
  __shared__ float red[2][TM3][4];
  const int t = threadIdx.x;
  const int nb = blockIdx.x * TM3;
  for(int i=t; i<TM3*HID; i+=256) hs[i>>7][i&127] = agg[nb*HID + i];
  if(t < TM3*3) xs[t/3][t%3] = x[nb*3 + t];
  __syncthreads();
  float acc[TM3][3] = {};
  const int c0 = t, c1 = t+256, c2 = t+512;
  for(int k=0; k<HID; ++k){
    const float w0 = Wl[k*ENC+c0], w1 = Wl[k*ENC+c1], w2 = Wl[k*ENC+c2];
    #pragma unroll
    for(int nn=0; nn<TM3; ++nn){
      const float hv = hs[nn][k];
      acc[nn][0] += hv*w0; acc[nn][1] += hv*w1; acc[nn][2] += hv*w2;
    }
  }
  const float add0 = b2l[c0]+bias2[c0], add1 = b2l[c1]+bias2[c1], add2 = b2l[c2]+bias2[c2];
  const float f00=Wfc[c0], f01=Wfc[ENC+c0], f02=Wfc[2*ENC+c0], bf0=bfc[c0];
  const float f10=Wfc[c1], f11=Wfc[ENC+c1], f12=Wfc[2*ENC+c1], bf1=bfc[c1];
  const float f20=Wfc[c2], f21=Wfc[ENC+c2], f22=Wfc[2*ENC+c2], bf2=bfc[c2];
  const int wid = t >> 6, lane = t & 63;
  #pragma unroll
  for(int nn=0; nn<TM3; ++nn){
    const float x0 = xs[nn][0], x1 = xs[nn][1], x2 = xs[nn][2];
    acc[nn][0] += add0 + x0*f00 + x1*f01 + x2*f02 + bf0;
    acc[nn][1] += add1 + x0*f10 + x1*f11 + x2*f12 + bf1;
    acc[nn][2] += add2 + x0*f20 + x1*f21 + x2*f22 + bf2;
  }
  #pragma unroll
  for(int nn=0; nn<TM3; ++nn){
    float s = acc[nn][0] + acc[nn][1] + acc[nn][2];
    float q = acc[nn][0]*acc[nn][0] + acc[nn][1]*acc[nn][1] + acc[nn][2]*acc[nn][2];
    s = wave_sum(s); q = wave_sum(q);
    if(lane == 0){ red[0][nn][wid] = s; red[1][nn][wid] = q; }
  }
  __syncthreads();
  const float gv0=gn[c0], gv1=gn[c1], gv2=gn[c2];
  const float bv0=bn[c0], bv1=bn[c1], bv2=bn[c2];
  #pragma unroll
  for(int nn=0; nn<TM3; ++nn){
    const float sum = red[0][nn][0]+red[0][nn][1]+red[0][nn][2]+red[0][nn][3];
    const float sq  = red[1][nn][0]+red[1][nn][1]+red[1][nn][2]+red[1][nn][3];
    const float mu  = sum * (1.f/ENC);
    const float var = sq * (1.f/ENC) - mu*mu;
    const float r = rsqrtf(var + EPSV);
    float* orow = out + (size_t)(nb+nn)*ENC;
    orow[c0] = (acc[nn][0]-mu)*r*gv0 + bv0;
    orow[c1] = (acc[nn][1]-mu)*r*gv1 + bv1;
    orow[c2] = (acc[nn][2]-mu)*r*gv2 + bv2;
  }
}

extern "C" void kernel_launch(void* const* d_in, const int* in_sizes, int n_in,
                              void* d_out, int out_size, void* d_ws, size_t ws_size,
                              hipStream_t stream) {
  const float* x    = (const float*)d_in[0];
  const int*   ei   = (const int*)  d_in[1];
  const float* Wfc  = (const float*)d_in[2];
  const float* bfc  = (const float*)d_in[3];
  const float* W1l  = (const float*)d_in[4];
  const float* b1l  = (const float*)d_in[5];
  const float* W1r  = (const float*)d_in[6];
  const float* b1r  = (const float*)d_in[7];
  const float* att1 = (const float*)d_in[8];
  const float* bias1= (const float*)d_in[9];
  const float* g1   = (const float*)d_in[10];
  const float* bb1  = (const float*)d_in[11];
  const float* W2l  = (const float*)d_in[12];
  const float* b2l  = (const float*)d_in[13];
  const float* W2r  = (const float*)d_in[14];
  const float* b2r  = (const float*)d_in[15];
  const float* att2 = (const float*)d_in[16];
  const float* bias2= (const float*)d_in[17];
  const float* gn   = (const float*)d_in[18];
  const float* bn   = (const float*)d_in[19];
  float* out = (float*)d_out;

  char* w = (char*)d_ws;
  auto alloc = [&](size_t bytes){ void* p = (void*)w; w += (bytes + 255) & ~(size_t)255; return p; };
  int*      hist     = (int*)     alloc((size_t)N_NODES*4);   // contiguous with cursor
  int*      cursor   = (int*)     alloc((size_t)N_NODES*4);
  int*      rowstart = (int*)     alloc((size_t)(N_NODES+1)*4);
  int*      ssrc     = (int*)     alloc((size_t)EP*4);
  float*    xl1      = (float*)   alloc((size_t)N_NODES*HID*4);
  float*    xr1      = (float*)   alloc((size_t)N_NODES*HID*4);
  u16*      h1b      = (u16*)     alloc((size_t)N_NODES*HID*2);
  float*    agg      = (float*)   alloc((size_t)N_NODES*HID*4);
  unsigned* xl2b     = (unsigned*)alloc((size_t)N_NODES*ENCP*4);
  unsigned* xr2b     = (unsigned*)alloc((size_t)N_NODES*ENCP*4);
  u16*      Wtb      = (u16*)     alloc((size_t)2*ENC*HID*2);

  hipMemsetAsync(hist, 0, (size_t)N_NODES*8, stream);   // hist + cursor

  lin1_kernel<<<N_NODES*HID/256, 256, 0, stream>>>(x, W1l, b1l, W1r, b1r, xl1, xr1);
  wprep_kernel<<<2*ENC*HID/256, 256, 0, stream>>>(W2l, W2r, Wtb);
  hist_kernel<<<EP/256, 256, 0, stream>>>(ei, hist);
  scan_kernel<<<1, 1024, 0, stream>>>(hist, rowstart);
  scatter_kernel<<<EP/256, 256, 0, stream>>>(ei, rowstart, cursor, ssrc);
  node1_kernel<<<N_NODES/4, 256, 0, stream>>>(xl1, xr1, att1, bias1, g1, bb1,
                                              rowstart, ssrc, h1b);
  mfma_lin2_kernel<<<dim3(N_NODES/LBM, 2*ENC/LBN), 256, 0, stream>>>(
      h1b, Wtb, b2l, b2r, (u16*)xl2b, (u16*)xr2b);
  node2b_kernel<<<N_NODES/4, 256, 0, stream>>>(xl2b, xr2b, att2, h1b,
                                               rowstart, ssrc, agg);
  gemm3_kernel<<<N_NODES/TM3, 256, 0, stream>>>(agg, W2l, b2l, bias2,
                                                x, Wfc, bfc, gn, bn, out);
}

// Round 4
// 223.056 us; speedup vs baseline: 1.5097x; 1.1275x over previous
//
#include <hip/hip_runtime.h>

#define N_NODES 16384
#define N_EDGES 262144
#define EP (N_EDGES + N_NODES)   // with self-loops
#define HID 128
#define ENC 768
#define ENCP (ENC/2)             // 384 bf16-pairs per row
#define NEG 0.2f
#define EPSV 1e-5f

typedef unsigned short u16;
using f32x4  = __attribute__((ext_vector_type(4))) float;
using bf16x8 = __attribute__((ext_vector_type(8))) short;

__device__ __forceinline__ float wave_sum(float v){
  #pragma unroll
  for(int m=32;m>=1;m>>=1) v += __shfl_xor(v, m, 64);
  return v;
}
__device__ __forceinline__ float lrelu(float v){ return v > 0.f ? v : NEG*v; }
__device__ __forceinline__ unsigned bf16rtne(float f){
  const unsigned u = __float_as_uint(f);
  return (u + 0x7fffu + ((u>>16)&1u)) >> 16;
}
__device__ __forceinline__ unsigned pack2(float a, float b){
  return bf16rtne(a) | (bf16rtne(b) << 16);
}
__device__ __forceinline__ float bf2f(u16 h){ return __uint_as_float(((unsigned)h) << 16); }
__device__ __forceinline__ float plo(unsigned u){ return __uint_as_float(u << 16); }
__device__ __forceinline__ float phi(unsigned u){ return __uint_as_float(u & 0xffff0000u); }

// ---- layer-1 transforms -> packed bf16 pairs (c, c+64): xl1p/xr1p [N][64] u32 ----
__global__ __launch_bounds__(256) void lin1_kernel(
    const float* __restrict__ x,
    const float* __restrict__ Wl, const float* __restrict__ bl,
    const float* __restrict__ Wr, const float* __restrict__ br,
    unsigned* __restrict__ xl1p, unsigned* __restrict__ xr1p){
  const int i = blockIdx.x*256 + threadIdx.x;        // exactly N*64 threads
  const int n = i >> 6, c = i & 63;
  const float x0 = x[n*3], x1 = x[n*3+1], x2 = x[n*3+2];
  const float la = x0*Wl[c]    + x1*Wl[HID+c]    + x2*Wl[2*HID+c]    + bl[c];
  const float lb = x0*Wl[c+64] + x1*Wl[HID+c+64] + x2*Wl[2*HID+c+64] + bl[c+64];
  const float ra = x0*Wr[c]    + x1*Wr[HID+c]    + x2*Wr[2*HID+c]    + br[c];
  const float rb = x0*Wr[c+64] + x1*Wr[HID+c+64] + x2*Wr[2*HID+c+64] + br[c+64];
  xl1p[i] = pack2(la, lb);
  xr1p[i] = pack2(ra, rb);
}

// ---- W2l/W2r -> transposed bf16 Wtb[1536][128] ----
__global__ __launch_bounds__(256) void wprep_kernel(
    const float* __restrict__ W2l, const float* __restrict__ W2r,
    u16* __restrict__ Wtb){
  const int idx = blockIdx.x*256 + threadIdx.x;      // 1536*128 threads
  const int n = idx >> 7, k = idx & 127;
  const float v = (n < ENC) ? W2l[k*ENC + n] : W2r[k*ENC + (n-ENC)];
  Wtb[idx] = (u16)bf16rtne(v);
}

// ---- CSR build: histogram of dst ----
__global__ __launch_bounds__(256) void hist_kernel(
    const int* __restrict__ ei, int* __restrict__ hist){
  const int i = blockIdx.x*256 + threadIdx.x;        // exactly EP threads
  const int dst = (i < N_EDGES) ? ei[N_EDGES + i] : (i - N_EDGES);
  atomicAdd(&hist[dst], 1);
}

// ---- single-block exclusive scan over N=16384 (1024 thr x 16 items) ----
__global__ __launch_bounds__(1024) void scan_kernel(
    const int* __restrict__ hist, int* __restrict__ rowstart){
  __shared__ int sums[1024];
  const int t = threadIdx.x;
  const int base = t*16;
  int loc[16];
  int s = 0;
  #pragma unroll
  for(int i=0;i<16;i++){ loc[i] = s; s += hist[base+i]; }
  sums[t] = s;
  __syncthreads();
  for(int off=1; off<1024; off<<=1){
    int v = 0;
    if(t >= off) v = sums[t-off];
    __syncthreads();
    if(t >= off) sums[t] += v;
    __syncthreads();
  }
  const int prev = (t==0) ? 0 : sums[t-1];
  #pragma unroll
  for(int i=0;i<16;i++) rowstart[base+i] = prev + loc[i];
  if(t == 1023) rowstart[N_NODES] = EP;
}

// ---- CSR build: scatter src ids into dst-sorted order ----
__global__ __launch_bounds__(256) void scatter_kernel(
    const int* __restrict__ ei, const int* __restrict__ rowstart,
    int* __restrict__ cursor, int* __restrict__ ssrc){
  const int i = blockIdx.x*256 + threadIdx.x;        // exactly EP threads
  const int src = (i < N_EDGES) ? ei[i]           : (i - N_EDGES);
  const int dst = (i < N_EDGES) ? ei[N_EDGES + i] : (i - N_EDGES);
  const int pos = rowstart[dst] + atomicAdd(&cursor[dst], 1);
  ssrc[pos] = src;
}

// ---- GAT layer 1, 2-edge unrolled; emits h1b [N][128] u16 + h1p [N][64] u32 ----
__global__ __launch_bounds__(256) void node1_kernel(
    const unsigned* __restrict__ xl1p, const unsigned* __restrict__ xr1p,
    const float* __restrict__ att1, const float* __restrict__ bias1,
    const float* __restrict__ g1, const float* __restrict__ b1,
    const int* __restrict__ rowstart, const int* __restrict__ ssrc,
    u16* __restrict__ h1b, unsigned* __restrict__ h1p){
  const int lane = threadIdx.x & 63;
  const int n = blockIdx.x*4 + (threadIdx.x >> 6);
  const unsigned xru = xr1p[n*64 + lane];
  const float xra = plo(xru), xrb = phi(xru);
  const float aa = att1[lane], ab = att1[lane+64];
  float acc0 = 0.f, acc1 = 0.f, denom = 0.f;
  int p = rowstart[n];
  const int p1 = rowstart[n+1];
  for(; p+1 < p1; p += 2){
    const int s0 = ssrc[p], s1 = ssrc[p+1];
    const unsigned u0 = xl1p[s0*64 + lane];
    const unsigned u1 = xl1p[s1*64 + lane];
    const float a0 = plo(u0), b0 = phi(u0);
    const float a1 = plo(u1), b1v = phi(u1);
    float q0 = lrelu(a0+xra)*aa + lrelu(b0+xrb)*ab;
    float q1 = lrelu(a1+xra)*aa + lrelu(b1v+xrb)*ab;
    #pragma unroll
    for(int m=32;m>=1;m>>=1){
      q0 += __shfl_xor(q0, m, 64);
      q1 += __shfl_xor(q1, m, 64);
    }
    const float w0 = expf(q0), w1 = expf(q1);
    denom += w0 + w1;
    acc0 += w0*a0 + w1*a1;
    acc1 += w0*b0 + w1*b1v;
  }
  if(p < p1){
    const int s0 = ssrc[p];
    const unsigned u0 = xl1p[s0*64 + lane];
    const float a0 = plo(u0), b0 = phi(u0);
    const float e = wave_sum(lrelu(a0+xra)*aa + lrelu(b0+xrb)*ab);
    const float w0 = expf(e);
    denom += w0; acc0 += w0*a0; acc1 += w0*b0;
  }
  const float inv = 1.f/denom;
  const float y0 = acc0*inv + bias1[lane];
  const float y1 = acc1*inv + bias1[lane+64];
  const float mu  = wave_sum(y0+y1) * (1.f/HID);
  const float d0 = y0-mu, d1 = y1-mu;
  const float var = wave_sum(d0*d0 + d1*d1) * (1.f/HID);
  const float r = rsqrtf(var + EPSV);
  float z0 = d0*r*g1[lane] + b1[lane];
  float z1 = d1*r*g1[lane+64] + b1[lane+64];
  z0 = z0 > 0.f ? z0 : expm1f(z0);        // ELU(alpha=1)
  z1 = z1 > 0.f ? z1 : expm1f(z1);
  h1b[n*HID+lane]    = (u16)bf16rtne(z0);
  h1b[n*HID+lane+64] = (u16)bf16rtne(z1);
  h1p[n*64+lane]     = pack2(z0, z1);
}

// ---- MFMA GEMM: [xl2b|xr2b](16384x1536) = h1b @ Wtb^T + bias; de-staged ----
#define LBM 128
#define LBN 128
__global__ __launch_bounds__(256) void mfma_lin2_kernel(
    const u16* __restrict__ h1b, const u16* __restrict__ Wtb,
    const float* __restrict__ b2l, const float* __restrict__ b2r,
    u16* __restrict__ xl2u, u16* __restrict__ xr2u){
  __shared__ __align__(16) u16 Cs[LBM*128];   // 32 KB bounce, swizzled 256B rows
  const int t = threadIdx.x;
  const int mb = blockIdx.x * LBM;
  const int nb = blockIdx.y * LBN;
  const int w = t >> 6, lane = t & 63;
  const int l15 = lane & 15, g = lane >> 4;
  const int ar0 = mb + w*32 + l15, ar1 = ar0 + 16;
  bf16x8 a0[4], a1[4];
  #pragma unroll
  for(int ks=0;ks<4;ks++){
    a0[ks] = *(const bf16x8*)(h1b + (size_t)ar0*128 + ks*32 + g*8);
    a1[ks] = *(const bf16x8*)(h1b + (size_t)ar1*128 + ks*32 + g*8);
  }
  f32x4 acc0[8], acc1[8];
  #pragma unroll
  for(int j=0;j<8;j++){ acc0[j]=(f32x4){0,0,0,0}; acc1[j]=(f32x4){0,0,0,0}; }
  #pragma unroll
  for(int j=0;j<8;j++){
    const int brn = nb + j*16 + l15;
    #pragma unroll
    for(int ks=0;ks<4;ks++){
      const bf16x8 b = *(const bf16x8*)(Wtb + (size_t)brn*128 + ks*32 + g*8);
      acc0[j] = __builtin_amdgcn_mfma_f32_16x16x32_bf16(a0[ks], b, acc0[j], 0,0,0);
      acc1[j] = __builtin_amdgcn_mfma_f32_16x16x32_bf16(a1[ks], b, acc1[j], 0,0,0);
    }
  }
  // epilogue: +bias (fp32), pack bf16 into Cs, then coalesced row writes
  const float* bsrc = (nb < ENC) ? (b2l + nb) : (b2r + (nb - ENC));
  float biasj[8];
  #pragma unroll
  for(int j=0;j<8;j++) biasj[j] = bsrc[j*16 + l15];
  #pragma unroll
  for(int j=0;j<8;j++){
    const int coll = j*16 + l15;              // C/D: col = lane&15 (verified)
    #pragma unroll
    for(int r4=0;r4<4;r4++){
      const int row0 = w*32 + g*4 + r4;       // C/D: row = (lane>>4)*4+reg
      *(u16*)((char*)Cs + row0*256 + ((coll*2) ^ ((row0&7)<<4))) =
          (u16)bf16rtne(acc0[j][r4] + biasj[j]);
      const int row1 = row0 + 16;
      *(u16*)((char*)Cs + row1*256 + ((coll*2) ^ ((row1&7)<<4))) =
          (u16)bf16rtne(acc1[j][r4] + biasj[j]);
    }
  }
  __syncthreads();
  u16* dst0 = (nb < ENC) ? (xl2u + nb) : (xr2u + (nb - ENC));
  const int rr = t >> 4, cc = t & 15;
  #pragma unroll
  for(int it=0; it<8; ++it){
    const int row = it*16 + rr;
    const uint4 v = *(const uint4*)((const char*)Cs + row*256 + ((cc*16) ^ ((row&7)<<4)));
    *(uint4*)(dst0 + (size_t)(mb+row)*ENC + cc*8) = v;
  }
}

// ---- GAT layer 2, 2-edge unrolled: bf16 scores, aggregate packed h1 -> aggb bf16 ----
__global__ __launch_bounds__(256) void node2b_kernel(
    const unsigned* __restrict__ xl2b, const unsigned* __restrict__ xr2b,
    const float* __restrict__ att2, const unsigned* __restrict__ h1p,
    const int* __restrict__ rowstart, const int* __restrict__ ssrc,
    u16* __restrict__ aggb){
  const int lane = threadIdx.x & 63;
  const int n = blockIdx.x*4 + (threadIdx.x >> 6);
  unsigned xrp[6]; float2 at[6];
  const unsigned* xrrow = xr2b + (size_t)n*ENCP;
  const float2* att22 = (const float2*)att2;
  #pragma unroll
  for(int j=0;j<6;j++){
    const int pidx = lane + 64*j;
    xrp[j] = xrrow[pidx]; at[j] = att22[pidx];
  }
  float denom = 0.f, acc0 = 0.f, acc1 = 0.f;
  int p = rowstart[n];
  const int p1 = rowstart[n+1];
  for(; p+1 < p1; p += 2){
    const int s0 = ssrc[p], s1 = ssrc[p+1];
    const unsigned* r0 = xl2b + (size_t)s0*ENCP;
    const unsigned* r1 = xl2b + (size_t)s1*ENCP;
    unsigned v0[6], v1[6];
    #pragma unroll
    for(int j=0;j<6;j++){ v0[j] = r0[lane + 64*j]; v1[j] = r1[lane + 64*j]; }
    const unsigned hu0 = h1p[s0*64 + lane];
    const unsigned hu1 = h1p[s1*64 + lane];
    float q0 = 0.f, q1 = 0.f;
    #pragma unroll
    for(int j=0;j<6;j++){
      q0 += lrelu(plo(v0[j])+plo(xrp[j]))*at[j].x + lrelu(phi(v0[j])+phi(xrp[j]))*at[j].y;
      q1 += lrelu(plo(v1[j])+plo(xrp[j]))*at[j].x + lrelu(phi(v1[j])+phi(xrp[j]))*at[j].y;
    }
    #pragma unroll
    for(int m=32;m>=1;m>>=1){
      q0 += __shfl_xor(q0, m, 64);
      q1 += __shfl_xor(q1, m, 64);
    }
    const float w0 = expf(q0), w1 = expf(q1);
    denom += w0 + w1;
    acc0 += w0*plo(hu0) + w1*plo(hu1);
    acc1 += w0*phi(hu0) + w1*phi(hu1);
  }
  if(p < p1){
    const int s0 = ssrc[p];
    const unsigned* r0 = xl2b + (size_t)s0*ENCP;
    unsigned v0[6];
    #pragma unroll
    for(int j=0;j<6;j++) v0[j] = r0[lane + 64*j];
    const unsigned hu0 = h1p[s0*64 + lane];
    float q0 = 0.f;
    #pragma unroll
    for(int j=0;j<6;j++)
      q0 += lrelu(plo(v0[j])+plo(xrp[j]))*at[j].x + lrelu(phi(v0[j])+phi(xrp[j]))*at[j].y;
    const float e = wave_sum(q0);
    const float w0 = expf(e);
    denom += w0; acc0 += w0*plo(hu0); acc1 += w0*phi(hu0);
  }
  const float inv = 1.f/denom;
  aggb[n*HID+lane]    = (u16)bf16rtne(acc0*inv);
  aggb[n*HID+lane+64] = (u16)bf16rtne(acc1*inv);
}

// ---- final fused: out = LN( aggb@W2l + b2l + bias2 + x@Wfc + bfc ) ----
// block = 64 rows x all 768 cols; A-frags in regs; B direct from L2; Ys bounce.
#define YSTR 770
__global__ __launch_bounds__(256) void gemm3_mfma_kernel(
    const u16* __restrict__ aggb, const u16* __restrict__ Wtb,
    const float* __restrict__ b2l, const float* __restrict__ bias2,
    const float* __restrict__ x, const float* __restrict__ Wfc,
    const float* __restrict__ bfc,
    const float* __restrict__ gn, const float* __restrict__ bn,
    float* __restrict__ out){
  __shared__ u16 Ys[64*YSTR];         // ~96 KB (padded stride: groups land on distinct banks)
  __shared__ float cbs[ENC];          // 3 KB : b2l + bias2 + bfc
  __shared__ float wfs[3][ENC];       // 9 KB
  __shared__ float mus[64], rss[64];
  const int t = threadIdx.x;
  const int mb = blockIdx.x * 64;
  for(int c=t; c<ENC; c+=256){
    cbs[c] = b2l[c] + bias2[c] + bfc[c];
    wfs[0][c] = Wfc[c]; wfs[1][c] = Wfc[ENC+c]; wfs[2][c] = Wfc[2*ENC+c];
  }
  const int w = t >> 6, lane = t & 63;
  const int l15 = lane & 15, g = lane >> 4;
  const int ar = mb + w*16 + l15;
  bf16x8 a[4];
  #pragma unroll
  for(int ks=0;ks<4;ks++)
    a[ks] = *(const bf16x8*)(aggb + (size_t)ar*128 + ks*32 + g*8);
  float xv0[4], xv1[4], xv2[4];
  #pragma unroll
  for(int r4=0;r4<4;r4++){
    const int rrow = mb + w*16 + g*4 + r4;
    xv0[r4] = x[rrow*3]; xv1[r4] = x[rrow*3+1]; xv2[r4] = x[rrow*3+2];
  }
  float rs[4] = {0,0,0,0}, rq[4] = {0,0,0,0};
  __syncthreads();
  #pragma unroll
  for(int sub=0; sub<6; ++sub){
    const int nb = sub*128;
    f32x4 acc[8];
    #pragma unroll
    for(int j=0;j<8;j++) acc[j]=(f32x4){0,0,0,0};
    #pragma unroll
    for(int j=0;j<8;j++){
      const int brn = nb + j*16 + l15;
      #pragma unroll
      for(int ks=0;ks<4;ks++){
        const bf16x8 b = *(const bf16x8*)(Wtb + (size_t)brn*128 + ks*32 + g*8);
        acc[j] = __builtin_amdgcn_mfma_f32_16x16x32_bf16(a[ks], b, acc[j], 0,0,0);
      }
    }
    #pragma unroll
    for(int j=0;j<8;j++){
      const int col = nb + j*16 + l15;
      const float cb = cbs[col];
      const float w0 = wfs[0][col], w1 = wfs[1][col], w2 = wfs[2][col];
      #pragma unroll
      for(int r4=0;r4<4;r4++){
        const int lrow = w*16 + g*4 + r4;
        const float y = acc[j][r4] + cb + xv0[r4]*w0 + xv1[r4]*w1 + xv2[r4]*w2;
        rs[r4] += y; rq[r4] += y*y;
        Ys[lrow*YSTR + col] = (u16)bf16rtne(y);
      }
    }
  }
  // reduce row stats across the 16 lanes of each group (masks <16 stay in-group)
  #pragma unroll
  for(int m=8;m>=1;m>>=1){
    #pragma unroll
    for(int r4=0;r4<4;r4++){
      rs[r4] += __shfl_xor(rs[r4], m, 64);
      rq[r4] += __shfl_xor(rq[r4], m, 64);
    }
  }
  if(l15 == 0){
    #pragma unroll
    for(int r4=0;r4<4;r4++){
      const int lrow = w*16 + g*4 + r4;
      const float mu = rs[r4] * (1.f/ENC);
      const float var = rq[r4] * (1.f/ENC) - mu*mu;
      mus[lrow] = mu;
      rss[lrow] = rsqrtf(var + EPSV);
    }
  }
  __syncthreads();
  float gv[12], bv[12];
  #pragma unroll
  for(int j2=0;j2<12;j2++){ gv[j2] = gn[lane + j2*64]; bv[j2] = bn[lane + j2*64]; }
  for(int r=0; r<16; ++r){
    const int lrow = w*16 + r;
    const float mu = mus[lrow], rstd = rss[lrow];
    float* orow = out + (size_t)(mb+lrow)*ENC;
    #pragma unroll
    for(int j2=0;j2<12;j2++){
      const float y = bf2f(Ys[lrow*YSTR + lane + j2*64]);
      orow[lane + j2*64] = (y - mu)*rstd*gv[j2] + bv[j2];
    }
  }
}

extern "C" void kernel_launch(void* const* d_in, const int* in_sizes, int n_in,
                              void* d_out, int out_size, void* d_ws, size_t ws_size,
                              hipStream_t stream) {
  const float* x    = (const float*)d_in[0];
  const int*   ei   = (const int*)  d_in[1];
  const float* Wfc  = (const float*)d_in[2];
  const float* bfc  = (const float*)d_in[3];
  const float* W1l  = (const float*)d_in[4];
  const float* b1l  = (const float*)d_in[5];
  const float* W1r  = (const float*)d_in[6];
  const float* b1r  = (const float*)d_in[7];
  const float* att1 = (const float*)d_in[8];
  const float* bias1= (const float*)d_in[9];
  const float* g1   = (const float*)d_in[10];
  const float* bb1  = (const float*)d_in[11];
  const float* W2l  = (const float*)d_in[12];
  const float* b2l  = (const float*)d_in[13];
  const float* W2r  = (const float*)d_in[14];
  const float* b2r  = (const float*)d_in[15];
  const float* att2 = (const float*)d_in[16];
  const float* bias2= (const float*)d_in[17];
  const float* gn   = (const float*)d_in[18];
  const float* bn   = (const float*)d_in[19];
  float* out = (float*)d_out;

  char* w = (char*)d_ws;
  auto alloc = [&](size_t bytes){ void* p = (void*)w; w += (bytes + 255) & ~(size_t)255; return p; };
  int*      hist     = (int*)     alloc((size_t)N_NODES*4);   // contiguous with cursor
  int*      cursor   = (int*)     alloc((size_t)N_NODES*4);
  int*      rowstart = (int*)     alloc((size_t)(N_NODES+1)*4);
  int*      ssrc     = (int*)     alloc((size_t)EP*4);
  unsigned* xl1p     = (unsigned*)alloc((size_t)N_NODES*64*4);
  unsigned* xr1p     = (unsigned*)alloc((size_t)N_NODES*64*4);
  u16*      h1b      = (u16*)     alloc((size_t)N_NODES*HID*2);
  unsigned* h1p      = (unsigned*)alloc((size_t)N_NODES*64*4);
  u16*      aggb     = (u16*)     alloc((size_t)N_NODES*HID*2);
  unsigned* xl2b     = (unsigned*)alloc((size_t)N_NODES*ENCP*4);
  unsigned* xr2b     = (unsigned*)alloc((size_t)N_NODES*ENCP*4);
  u16*      Wtb      = (u16*)     alloc((size_t)2*ENC*HID*2);

  hipMemsetAsync(hist, 0, (size_t)N_NODES*8, stream);   // hist + cursor

  lin1_kernel<<<N_NODES*64/256, 256, 0, stream>>>(x, W1l, b1l, W1r, b1r, xl1p, xr1p);
  wprep_kernel<<<2*ENC*HID/256, 256, 0, stream>>>(W2l, W2r, Wtb);
  hist_kernel<<<EP/256, 256, 0, stream>>>(ei, hist);
  scan_kernel<<<1, 1024, 0, stream>>>(hist, rowstart);
  scatter_kernel<<<EP/256, 256, 0, stream>>>(ei, rowstart, cursor, ssrc);
  node1_kernel<<<N_NODES/4, 256, 0, stream>>>(xl1p, xr1p, att1, bias1, g1, bb1,
                                              rowstart, ssrc, h1b, h1p);
  mfma_lin2_kernel<<<dim3(N_NODES/LBM, 2*ENC/LBN), 256, 0, stream>>>(
      h1b, Wtb, b2l, b2r, (u16*)xl2b, (u16*)xr2b);
  node2b_kernel<<<N_NODES/4, 256, 0, stream>>>(xl2b, xr2b, att2, h1p,
                                               rowstart, ssrc, aggb);
  gemm3_mfma_kernel<<<N_NODES/64, 256, 0, stream>>>(aggb, Wtb, b2l, bias2,
                                                    x, Wfc, bfc, gn, bn, out);
}

// Round 5
// 216.889 us; speedup vs baseline: 1.5527x; 1.0284x over previous
//
#include <hip/hip_runtime.h>

#define N_NODES 16384
#define N_EDGES 262144
#define EP (N_EDGES + N_NODES)   // with self-loops
#define HID 128
#define ENC 768
#define ENCP (ENC/2)             // 384 bf16-pairs per row
#define EPSV 1e-5f

typedef unsigned short u16;
using f32x4  = __attribute__((ext_vector_type(4))) float;
using bf16x8 = __attribute__((ext_vector_type(8))) short;

__device__ __forceinline__ float wave_sum(float v){
  #pragma unroll
  for(int m=32;m>=1;m>>=1) v += __shfl_xor(v, m, 64);
  return v;
}
__device__ __forceinline__ unsigned bf16rtne(float f){
  const unsigned u = __float_as_uint(f);
  return (u + 0x7fffu + ((u>>16)&1u)) >> 16;
}
__device__ __forceinline__ unsigned pack2(float a, float b){
  return bf16rtne(a) | (bf16rtne(b) << 16);
}
__device__ __forceinline__ float bf2f(u16 h){ return __uint_as_float(((unsigned)h) << 16); }
__device__ __forceinline__ float plo(unsigned u){ return __uint_as_float(u << 16); }
__device__ __forceinline__ float phi(unsigned u){ return __uint_as_float(u & 0xffff0000u); }

// ---- merged prep: lin1 (+att1 dots), Wtb transpose, dst histogram, W2@att2 ----
#define LIN1_BLKS (N_NODES/4)            // 4096 (one wave per node)
#define WPREP_BLKS (2*ENC*HID/256)       // 768
#define HIST_BLKS (EP/256)               // 1088
#define W2A_BLKS 258                     // 128 l + 128 r + cl + cr
__global__ __launch_bounds__(256) void prep_kernel(
    const float* __restrict__ x,
    const float* __restrict__ W1l, const float* __restrict__ b1l,
    const float* __restrict__ W1r, const float* __restrict__ b1r,
    const float* __restrict__ att1,
    const float* __restrict__ W2l, const float* __restrict__ W2r,
    const float* __restrict__ b2l, const float* __restrict__ b2r,
    const float* __restrict__ att2,
    const int* __restrict__ ei,
    unsigned* __restrict__ xl1p, unsigned* __restrict__ xr1p,
    float* __restrict__ dotl1, float* __restrict__ dotr1,
    u16* __restrict__ Wtb, float* __restrict__ w2a,
    int* __restrict__ hist){
  const int bid = blockIdx.x;
  if(bid < LIN1_BLKS){
    const int lane = threadIdx.x & 63;
    const int n = bid*4 + (threadIdx.x >> 6);
    const float x0 = x[n*3], x1 = x[n*3+1], x2 = x[n*3+2];
    const int c0 = lane, c1 = lane + 64;
    const float la = x0*W1l[c0] + x1*W1l[HID+c0] + x2*W1l[2*HID+c0] + b1l[c0];
    const float lb = x0*W1l[c1] + x1*W1l[HID+c1] + x2*W1l[2*HID+c1] + b1l[c1];
    const float ra = x0*W1r[c0] + x1*W1r[HID+c0] + x2*W1r[2*HID+c0] + b1r[c0];
    const float rb = x0*W1r[c1] + x1*W1r[HID+c1] + x2*W1r[2*HID+c1] + b1r[c1];
    const float aa = att1[c0], ab = att1[c1];
    const float dl = wave_sum(la*aa + lb*ab);
    const float dr = wave_sum(ra*aa + rb*ab);
    if(lane == 0){ dotl1[n] = 0.6f*dl; dotr1[n] = 0.6f*dr; }
    xl1p[n*64+lane] = pack2(la, lb);
    xr1p[n*64+lane] = pack2(ra, rb);
  } else if(bid < LIN1_BLKS + WPREP_BLKS){
    const int idx = (bid - LIN1_BLKS)*256 + threadIdx.x;
    const int n = idx >> 7, k = idx & 127;
    const float v = (n < ENC) ? W2l[k*ENC + n] : W2r[k*ENC + (n-ENC)];
    Wtb[idx] = (u16)bf16rtne(v);
  } else if(bid < LIN1_BLKS + WPREP_BLKS + HIST_BLKS){
    const int i = (bid - LIN1_BLKS - WPREP_BLKS)*256 + threadIdx.x;
    const int dst = (i < N_EDGES) ? ei[N_EDGES + i] : (i - N_EDGES);
    atomicAdd(&hist[dst], 1);
  } else {
    // w2a[idx]: idx<128 -> W2l@att2 row k; idx<256 -> W2r@att2; 256/257 -> att2.b2l / att2.b2r
    const int idx = bid - (LIN1_BLKS + WPREP_BLKS + HIST_BLKS);
    const float* src = (idx < 128) ? (W2l + (size_t)idx*ENC)
                     : (idx < 256) ? (W2r + (size_t)(idx-128)*ENC)
                     : (idx == 256) ? b2l : b2r;
    float partial = 0.f;
    for(int c = threadIdx.x; c < ENC; c += 256) partial += src[c]*att2[c];
    partial = wave_sum(partial);
    __shared__ float red4[4];
    if((threadIdx.x & 63) == 0) red4[threadIdx.x >> 6] = partial;
    __syncthreads();
    if(threadIdx.x == 0) w2a[idx] = red4[0]+red4[1]+red4[2]+red4[3];
  }
}

// ---- single-block exclusive scan over N=16384 (1024 thr x 16 items) ----
__global__ __launch_bounds__(1024) void scan_kernel(
    const int* __restrict__ hist, int* __restrict__ rowstart){
  __shared__ int sums[1024];
  const int t = threadIdx.x;
  const int base = t*16;
  int loc[16];
  int s = 0;
  #pragma unroll
  for(int i=0;i<16;i++){ loc[i] = s; s += hist[base+i]; }
  sums[t] = s;
  __syncthreads();
  for(int off=1; off<1024; off<<=1){
    int v = 0;
    if(t >= off) v = sums[t-off];
    __syncthreads();
    if(t >= off) sums[t] += v;
    __syncthreads();
  }
  const int prev = (t==0) ? 0 : sums[t-1];
  #pragma unroll
  for(int i=0;i<16;i++) rowstart[base+i] = prev + loc[i];
  if(t == 1023) rowstart[N_NODES] = EP;
}

// ---- CSR build: scatter src ids into dst-sorted order ----
__global__ __launch_bounds__(256) void scatter_kernel(
    const int* __restrict__ ei, const int* __restrict__ rowstart,
    int* __restrict__ cursor, int* __restrict__ ssrc){
  const int i = blockIdx.x*256 + threadIdx.x;        // exactly EP threads
  const int src = (i < N_EDGES) ? ei[i]           : (i - N_EDGES);
  const int dst = (i < N_EDGES) ? ei[N_EDGES + i] : (i - N_EDGES);
  const int pos = rowstart[dst] + atomicAdd(&cursor[dst], 1);
  ssrc[pos] = src;
}

// ---- GAT layer 1 (abs-decomposed scores), emits h1b/h1p + layer-2 node dots ----
__global__ __launch_bounds__(256) void node1_kernel(
    const unsigned* __restrict__ xl1p, const unsigned* __restrict__ xr1p,
    const float* __restrict__ att1,
    const float* __restrict__ dotl1, const float* __restrict__ dotr1,
    const float* __restrict__ bias1,
    const float* __restrict__ g1, const float* __restrict__ b1,
    const float* __restrict__ w2a,
    const int* __restrict__ rowstart, const int* __restrict__ ssrc,
    u16* __restrict__ h1b, unsigned* __restrict__ h1p,
    float* __restrict__ dotl2, float* __restrict__ dotr2){
  const int lane = threadIdx.x & 63;
  const int n = blockIdx.x*4 + (threadIdx.x >> 6);
  const unsigned xru = xr1p[n*64 + lane];
  const float xra = plo(xru), xrb = phi(xru);
  const float sa = 0.4f*att1[lane], sb = 0.4f*att1[lane+64];
  const float ebase = dotr1[n];
  float acc0 = 0.f, acc1 = 0.f, denom = 0.f;
  int p = rowstart[n];
  const int p1 = rowstart[n+1];
  for(; p+1 < p1; p += 2){
    const int s0 = ssrc[p], s1 = ssrc[p+1];
    const unsigned u0 = xl1p[s0*64 + lane];
    const unsigned u1 = xl1p[s1*64 + lane];
    const float dl0 = dotl1[s0], dl1 = dotl1[s1];
    const float a0 = plo(u0), b0 = phi(u0);
    const float a1 = plo(u1), b1v = phi(u1);
    float q0 = fmaf(sa, __builtin_fabsf(a0+xra), sb*__builtin_fabsf(b0+xrb));
    float q1 = fmaf(sa, __builtin_fabsf(a1+xra), sb*__builtin_fabsf(b1v+xrb));
    #pragma unroll
    for(int m=32;m>=1;m>>=1){
      q0 += __shfl_xor(q0, m, 64);
      q1 += __shfl_xor(q1, m, 64);
    }
    const float w0 = __expf(q0 + dl0 + ebase), w1 = __expf(q1 + dl1 + ebase);
    denom += w0 + w1;
    acc0 += w0*a0 + w1*a1;
    acc1 += w0*b0 + w1*b1v;
  }
  if(p < p1){
    const int s0 = ssrc[p];
    const unsigned u0 = xl1p[s0*64 + lane];
    const float a0 = plo(u0), b0 = phi(u0);
    const float q = wave_sum(fmaf(sa, __builtin_fabsf(a0+xra), sb*__builtin_fabsf(b0+xrb)));
    const float w0 = __expf(q + dotl1[s0] + ebase);
    denom += w0; acc0 += w0*a0; acc1 += w0*b0;
  }
  const float inv = 1.f/denom;
  const float y0 = acc0*inv + bias1[lane];
  const float y1 = acc1*inv + bias1[lane+64];
  const float mu  = wave_sum(y0+y1) * (1.f/HID);
  const float d0 = y0-mu, d1 = y1-mu;
  const float var = wave_sum(d0*d0 + d1*d1) * (1.f/HID);
  const float r = rsqrtf(var + EPSV);
  float z0 = d0*r*g1[lane] + b1[lane];
  float z1 = d1*r*g1[lane+64] + b1[lane+64];
  z0 = z0 > 0.f ? z0 : expm1f(z0);        // ELU(alpha=1)
  z1 = z1 > 0.f ? z1 : expm1f(z1);
  h1b[n*HID+lane]    = (u16)bf16rtne(z0);
  h1b[n*HID+lane+64] = (u16)bf16rtne(z1);
  h1p[n*64+lane]     = pack2(z0, z1);
  // layer-2 per-node linear score terms: 0.6*(att2 . xl2/xr2[n])
  float dl2 = z0*w2a[lane]     + z1*w2a[lane+64];
  float dr2 = z0*w2a[128+lane] + z1*w2a[128+lane+64];
  #pragma unroll
  for(int m=32;m>=1;m>>=1){
    dl2 += __shfl_xor(dl2, m, 64);
    dr2 += __shfl_xor(dr2, m, 64);
  }
  if(lane == 0){
    dotl2[n] = 0.6f*(dl2 + w2a[256]);
    dotr2[n] = 0.6f*(dr2 + w2a[257]);
  }
}

// ---- MFMA GEMM: [xl2b|xr2b](16384x1536) = h1b @ Wtb^T + bias; de-staged ----
#define LBM 128
#define LBN 128
__global__ __launch_bounds__(256) void mfma_lin2_kernel(
    const u16* __restrict__ h1b, const u16* __restrict__ Wtb,
    const float* __restrict__ b2l, const float* __restrict__ b2r,
    u16* __restrict__ xl2u, u16* __restrict__ xr2u){
  __shared__ __align__(16) u16 Cs[LBM*128];   // 32 KB bounce, swizzled 256B rows
  const int t = threadIdx.x;
  const int mb = blockIdx.x * LBM;
  const int nb = blockIdx.y * LBN;
  const int w = t >> 6, lane = t & 63;
  const int l15 = lane & 15, g = lane >> 4;
  const int ar0 = mb + w*32 + l15, ar1 = ar0 + 16;
  bf16x8 a0[4], a1[4];
  #pragma unroll
  for(int ks=0;ks<4;ks++){
    a0[ks] = *(const bf16x8*)(h1b + (size_t)ar0*128 + ks*32 + g*8);
    a1[ks] = *(const bf16x8*)(h1b + (size_t)ar1*128 + ks*32 + g*8);
  }
  f32x4 acc0[8], acc1[8];
  #pragma unroll
  for(int j=0;j<8;j++){ acc0[j]=(f32x4){0,0,0,0}; acc1[j]=(f32x4){0,0,0,0}; }
  #pragma unroll
  for(int j=0;j<8;j++){
    const int brn = nb + j*16 + l15;
    #pragma unroll
    for(int ks=0;ks<4;ks++){
      const bf16x8 b = *(const bf16x8*)(Wtb + (size_t)brn*128 + ks*32 + g*8);
      acc0[j] = __builtin_amdgcn_mfma_f32_16x16x32_bf16(a0[ks], b, acc0[j], 0,0,0);
      acc1[j] = __builtin_amdgcn_mfma_f32_16x16x32_bf16(a1[ks], b, acc1[j], 0,0,0);
    }
  }
  const float* bsrc = (nb < ENC) ? (b2l + nb) : (b2r + (nb - ENC));
  float biasj[8];
  #pragma unroll
  for(int j=0;j<8;j++) biasj[j] = bsrc[j*16 + l15];
  #pragma unroll
  for(int j=0;j<8;j++){
    const int coll = j*16 + l15;              // C/D: col = lane&15 (verified)
    #pragma unroll
    for(int r4=0;r4<4;r4++){
      const int row0 = w*32 + g*4 + r4;       // C/D: row = (lane>>4)*4+reg
      *(u16*)((char*)Cs + row0*256 + ((coll*2) ^ ((row0&7)<<4))) =
          (u16)bf16rtne(acc0[j][r4] + biasj[j]);
      const int row1 = row0 + 16;
      *(u16*)((char*)Cs + row1*256 + ((coll*2) ^ ((row1&7)<<4))) =
          (u16)bf16rtne(acc1[j][r4] + biasj[j]);
    }
  }
  __syncthreads();
  u16* dst0 = (nb < ENC) ? (xl2u + nb) : (xr2u + (nb - ENC));
  const int rr = t >> 4, cc = t & 15;
  #pragma unroll
  for(int it=0; it<8; ++it){
    const int row = it*16 + rr;
    const uint4 v = *(const uint4*)((const char*)Cs + row*256 + ((cc*16) ^ ((row&7)<<4)));
    *(uint4*)(dst0 + (size_t)(mb+row)*ENC + cc*8) = v;
  }
}

// ---- GAT layer 2 (abs-decomposed scores), aggregate packed h1 -> aggb bf16 ----
__global__ __launch_bounds__(256) void node2b_kernel(
    const unsigned* __restrict__ xl2b, const unsigned* __restrict__ xr2b,
    const float* __restrict__ att2,
    const float* __restrict__ dotl2, const float* __restrict__ dotr2,
    const unsigned* __restrict__ h1p,
    const int* __restrict__ rowstart, const int* __restrict__ ssrc,
    u16* __restrict__ aggb){
  const int lane = threadIdx.x & 63;
  const int n = blockIdx.x*4 + (threadIdx.x >> 6);
  const uint2* xrrow = (const uint2*)(xr2b + (size_t)n*ENCP);
  float xr[12], sg[12];
  #pragma unroll
  for(int k=0;k<3;k++){
    const uint2 u = xrrow[lane + 64*k];
    xr[4*k]   = plo(u.x); xr[4*k+1] = phi(u.x);
    xr[4*k+2] = plo(u.y); xr[4*k+3] = phi(u.y);
    const int cb = 4*(lane + 64*k);
    sg[4*k]   = 0.4f*att2[cb];   sg[4*k+1] = 0.4f*att2[cb+1];
    sg[4*k+2] = 0.4f*att2[cb+2]; sg[4*k+3] = 0.4f*att2[cb+3];
  }
  const float ebase = dotr2[n];
  float denom = 0.f, acc0 = 0.f, acc1 = 0.f;
  int p = rowstart[n];
  const int p1 = rowstart[n+1];
  for(; p+1 < p1; p += 2){
    const int s0 = ssrc[p], s1 = ssrc[p+1];
    const uint2* r0 = (const uint2*)(xl2b + (size_t)s0*ENCP);
    const uint2* r1 = (const uint2*)(xl2b + (size_t)s1*ENCP);
    uint2 v0[3], v1[3];
    #pragma unroll
    for(int k=0;k<3;k++){ v0[k] = r0[lane + 64*k]; v1[k] = r1[lane + 64*k]; }
    const float dl0 = dotl2[s0], dl1 = dotl2[s1];
    const unsigned hu0 = h1p[s0*64 + lane];
    const unsigned hu1 = h1p[s1*64 + lane];
    float q0 = 0.f, q1 = 0.f;
    #pragma unroll
    for(int k=0;k<3;k++){
      q0 = fmaf(sg[4*k],   __builtin_fabsf(plo(v0[k].x)+xr[4*k]),   q0);
      q0 = fmaf(sg[4*k+1], __builtin_fabsf(phi(v0[k].x)+xr[4*k+1]), q0);
      q0 = fmaf(sg[4*k+2], __builtin_fabsf(plo(v0[k].y)+xr[4*k+2]), q0);
      q0 = fmaf(sg[4*k+3], __builtin_fabsf(phi(v0[k].y)+xr[4*k+3]), q0);
      q1 = fmaf(sg[4*k],   __builtin_fabsf(plo(v1[k].x)+xr[4*k]),   q1);
      q1 = fmaf(sg[4*k+1], __builtin_fabsf(phi(v1[k].x)+xr[4*k+1]), q1);
      q1 = fmaf(sg[4*k+2], __builtin_fabsf(plo(v1[k].y)+xr[4*k+2]), q1);
      q1 = fmaf(sg[4*k+3], __builtin_fabsf(phi(v1[k].y)+xr[4*k+3]), q1);
    }
    #pragma unroll
    for(int m=32;m>=1;m>>=1){
      q0 += __shfl_xor(q0, m, 64);
      q1 += __shfl_xor(q1, m, 64);
    }
    const float w0 = __expf(q0 + dl0 + ebase), w1 = __expf(q1 + dl1 + ebase);
    denom += w0 + w1;
    acc0 += w0*plo(hu0) + w1*plo(hu1);
    acc1 += w0*phi(hu0) + w1*phi(hu1);
  }
  if(p < p1){
    const int s0 = ssrc[p];
    const uint2* r0 = (const uint2*)(xl2b + (size_t)s0*ENCP);
    float q0 = 0.f;
    #pragma unroll
    for(int k=0;k<3;k++){
      const uint2 v = r0[lane + 64*k];
      q0 = fmaf(sg[4*k],   __builtin_fabsf(plo(v.x)+xr[4*k]),   q0);
      q0 = fmaf(sg[4*k+1], __builtin_fabsf(phi(v.x)+xr[4*k+1]), q0);
      q0 = fmaf(sg[4*k+2], __builtin_fabsf(plo(v.y)+xr[4*k+2]), q0);
      q0 = fmaf(sg[4*k+3], __builtin_fabsf(phi(v.y)+xr[4*k+3]), q0);
    }
    const unsigned hu0 = h1p[s0*64 + lane];
    const float w0 = __expf(wave_sum(q0) + dotl2[s0] + ebase);
    denom += w0; acc0 += w0*plo(hu0); acc1 += w0*phi(hu0);
  }
  const float inv = 1.f/denom;
  aggb[n*HID+lane]    = (u16)bf16rtne(acc0*inv);
  aggb[n*HID+lane+64] = (u16)bf16rtne(acc1*inv);
}

// ---- final fused: out = LN( aggb@W2l + b2l + bias2 + x@Wfc + bfc ) ----
#define YSTR 770
__global__ __launch_bounds__(256) void gemm3_mfma_kernel(
    const u16* __restrict__ aggb, const u16* __restrict__ Wtb,
    const float* __restrict__ b2l, const float* __restrict__ bias2,
    const float* __restrict__ x, const float* __restrict__ Wfc,
    const float* __restrict__ bfc,
    const float* __restrict__ gn, const float* __restrict__ bn,
    float* __restrict__ out){
  __shared__ u16 Ys[64*YSTR];
  __shared__ float cbs[ENC];
  __shared__ float wfs[3][ENC];
  __shared__ float mus[64], rss[64];
  const int t = threadIdx.x;
  const int mb = blockIdx.x * 64;
  for(int c=t; c<ENC; c+=256){
    cbs[c] = b2l[c] + bias2[c] + bfc[c];
    wfs[0][c] = Wfc[c]; wfs[1][c] = Wfc[ENC+c]; wfs[2][c] = Wfc[2*ENC+c];
  }
  const int w = t >> 6, lane = t & 63;
  const int l15 = lane & 15, g = lane >> 4;
  const int ar = mb + w*16 + l15;
  bf16x8 a[4];
  #pragma unroll
  for(int ks=0;ks<4;ks++)
    a[ks] = *(const bf16x8*)(aggb + (size_t)ar*128 + ks*32 + g*8);
  float xv0[4], xv1[4], xv2[4];
  #pragma unroll
  for(int r4=0;r4<4;r4++){
    const int rrow = mb + w*16 + g*4 + r4;
    xv0[r4] = x[rrow*3]; xv1[r4] = x[rrow*3+1]; xv2[r4] = x[rrow*3+2];
  }
  float rs[4] = {0,0,0,0}, rq[4] = {0,0,0,0};
  __syncthreads();
  #pragma unroll
  for(int sub=0; sub<6; ++sub){
    const int nb = sub*128;
    f32x4 acc[8];
    #pragma unroll
    for(int j=0;j<8;j++) acc[j]=(f32x4){0,0,0,0};
    #pragma unroll
    for(int j=0;j<8;j++){
      const int brn = nb + j*16 + l15;
      #pragma unroll
      for(int ks=0;ks<4;ks++){
        const bf16x8 b = *(const bf16x8*)(Wtb + (size_t)brn*128 + ks*32 + g*8);
        acc[j] = __builtin_amdgcn_mfma_f32_16x16x32_bf16(a[ks], b, acc[j], 0,0,0);
      }
    }
    #pragma unroll
    for(int j=0;j<8;j++){
      const int col = nb + j*16 + l15;
      const float cb = cbs[col];
      const float w0 = wfs[0][col], w1 = wfs[1][col], w2 = wfs[2][col];
      #pragma unroll
      for(int r4=0;r4<4;r4++){
        const int lrow = w*16 + g*4 + r4;
        const float y = acc[j][r4] + cb + xv0[r4]*w0 + xv1[r4]*w1 + xv2[r4]*w2;
        rs[r4] += y; rq[r4] += y*y;
        Ys[lrow*YSTR + col] = (u16)bf16rtne(y);
      }
    }
  }
  #pragma unroll
  for(int m=8;m>=1;m>>=1){
    #pragma unroll
    for(int r4=0;r4<4;r4++){
      rs[r4] += __shfl_xor(rs[r4], m, 64);
      rq[r4] += __shfl_xor(rq[r4], m, 64);
    }
  }
  if(l15 == 0){
    #pragma unroll
    for(int r4=0;r4<4;r4++){
      const int lrow = w*16 + g*4 + r4;
      const float mu = rs[r4] * (1.f/ENC);
      const float var = rq[r4] * (1.f/ENC) - mu*mu;
      mus[lrow] = mu;
      rss[lrow] = rsqrtf(var + EPSV);
    }
  }
  __syncthreads();
  float gv[12], bv[12];
  #pragma unroll
  for(int j2=0;j2<12;j2++){ gv[j2] = gn[lane + j2*64]; bv[j2] = bn[lane + j2*64]; }
  for(int r=0; r<16; ++r){
    const int lrow = w*16 + r;
    const float mu = mus[lrow], rstd = rss[lrow];
    float* orow = out + (size_t)(mb+lrow)*ENC;
    #pragma unroll
    for(int j2=0;j2<12;j2++){
      const float y = bf2f(Ys[lrow*YSTR + lane + j2*64]);
      orow[lane + j2*64] = (y - mu)*rstd*gv[j2] + bv[j2];
    }
  }
}

extern "C" void kernel_launch(void* const* d_in, const int* in_sizes, int n_in,
                              void* d_out, int out_size, void* d_ws, size_t ws_size,
                              hipStream_t stream) {
  const float* x    = (const float*)d_in[0];
  const int*   ei   = (const int*)  d_in[1];
  const float* Wfc  = (const float*)d_in[2];
  const float* bfc  = (const float*)d_in[3];
  const float* W1l  = (const float*)d_in[4];
  const float* b1l  = (const float*)d_in[5];
  const float* W1r  = (const float*)d_in[6];
  const float* b1r  = (const float*)d_in[7];
  const float* att1 = (const float*)d_in[8];
  const float* bias1= (const float*)d_in[9];
  const float* g1   = (const float*)d_in[10];
  const float* bb1  = (const float*)d_in[11];
  const float* W2l  = (const float*)d_in[12];
  const float* b2l  = (const float*)d_in[13];
  const float* W2r  = (const float*)d_in[14];
  const float* b2r  = (const float*)d_in[15];
  const float* att2 = (const float*)d_in[16];
  const float* bias2= (const float*)d_in[17];
  const float* gn   = (const float*)d_in[18];
  const float* bn   = (const float*)d_in[19];
  float* out = (float*)d_out;

  char* w = (char*)d_ws;
  auto alloc = [&](size_t bytes){ void* p = (void*)w; w += (bytes + 255) & ~(size_t)255; return p; };
  int*      hist     = (int*)     alloc((size_t)N_NODES*4);   // contiguous with cursor
  int*      cursor   = (int*)     alloc((size_t)N_NODES*4);
  int*      rowstart = (int*)     alloc((size_t)(N_NODES+1)*4);
  int*      ssrc     = (int*)     alloc((size_t)EP*4);
  unsigned* xl1p     = (unsigned*)alloc((size_t)N_NODES*64*4);
  unsigned* xr1p     = (unsigned*)alloc((size_t)N_NODES*64*4);
  float*    dotl1    = (float*)   alloc((size_t)N_NODES*4);
  float*    dotr1    = (float*)   alloc((size_t)N_NODES*4);
  float*    dotl2    = (float*)   alloc((size_t)N_NODES*4);
  float*    dotr2    = (float*)   alloc((size_t)N_NODES*4);
  u16*      h1b      = (u16*)     alloc((size_t)N_NODES*HID*2);
  unsigned* h1p      = (unsigned*)alloc((size_t)N_NODES*64*4);
  u16*      aggb     = (u16*)     alloc((size_t)N_NODES*HID*2);
  unsigned* xl2b     = (unsigned*)alloc((size_t)N_NODES*ENCP*4);
  unsigned* xr2b     = (unsigned*)alloc((size_t)N_NODES*ENCP*4);
  u16*      Wtb      = (u16*)     alloc((size_t)2*ENC*HID*2);
  float*    w2a      = (float*)   alloc((size_t)W2A_BLKS*4);

  hipMemsetAsync(hist, 0, (size_t)N_NODES*8, stream);   // hist + cursor

  prep_kernel<<<LIN1_BLKS+WPREP_BLKS+HIST_BLKS+W2A_BLKS, 256, 0, stream>>>(
      x, W1l, b1l, W1r, b1r, att1, W2l, W2r, b2l, b2r, att2, ei,
      xl1p, xr1p, dotl1, dotr1, Wtb, w2a, hist);
  scan_kernel<<<1, 1024, 0, stream>>>(hist, rowstart);
  scatter_kernel<<<EP/256, 256, 0, stream>>>(ei, rowstart, cursor, ssrc);
  node1_kernel<<<N_NODES/4, 256, 0, stream>>>(xl1p, xr1p, att1, dotl1, dotr1,
                                              bias1, g1, bb1, w2a,
                                              rowstart, ssrc, h1b, h1p, dotl2, dotr2);
  mfma_lin2_kernel<<<dim3(N_NODES/LBM, 2*ENC/LBN), 256, 0, stream>>>(
      h1b, Wtb, b2l, b2r, (u16*)xl2b, (u16*)xr2b);
  node2b_kernel<<<N_NODES/4, 256, 0, stream>>>(xl2b, xr2b, att2, dotl2, dotr2,
                                               h1p, rowstart, ssrc, aggb);
  gemm3_mfma_kernel<<<N_NODES/64, 256, 0, stream>>>(aggb, Wtb, b2l, bias2,
                                                    x, Wfc, bfc, gn, bn, out);
}

// Round 6
// 192.677 us; speedup vs baseline: 1.7478x; 1.1257x over previous
//
#include <hip/hip_runtime.h>

#define N_NODES 16384
#define N_EDGES 262144
#define EP (N_EDGES + N_NODES)   // with self-loops
#define HID 128
#define ENC 768
#define ENCP (ENC/2)             // 384 bf16-pairs per row
#define EPSV 1e-5f

typedef unsigned short u16;
typedef unsigned char u8;
using f32x4  = __attribute__((ext_vector_type(4))) float;
using bf16x8 = __attribute__((ext_vector_type(8))) short;
using v2f    = __attribute__((ext_vector_type(2))) float;

__device__ __forceinline__ float wave_sum(float v){
  #pragma unroll
  for(int m=32;m>=1;m>>=1) v += __shfl_xor(v, m, 64);
  return v;
}
__device__ __forceinline__ unsigned bf16rtne(float f){
  const unsigned u = __float_as_uint(f);
  return (u + 0x7fffu + ((u>>16)&1u)) >> 16;
}
__device__ __forceinline__ unsigned pack2(float a, float b){
  return bf16rtne(a) | (bf16rtne(b) << 16);
}
__device__ __forceinline__ float bf2f(u16 h){ return __uint_as_float(((unsigned)h) << 16); }
__device__ __forceinline__ float plo(unsigned u){ return __uint_as_float(u << 16); }
__device__ __forceinline__ float phi(unsigned u){ return __uint_as_float(u & 0xffff0000u); }
__device__ __forceinline__ u8 f2fp8(float v){
  return (u8)(__builtin_amdgcn_cvt_pk_fp8_f32(v, v, 0, false) & 0xff);
}

// ---- merged prep: lin1 (+att1 dots), Wtb transpose, dst histogram, W2@att2 ----
#define LIN1_BLKS (N_NODES/4)            // 4096 (one wave per node)
#define WPREP_BLKS (2*ENC*HID/256)       // 768
#define HIST_BLKS (EP/256)               // 1088
#define W2A_BLKS 258                     // 128 l + 128 r + cl + cr
__global__ __launch_bounds__(256) void prep_kernel(
    const float* __restrict__ x,
    const float* __restrict__ W1l, const float* __restrict__ b1l,
    const float* __restrict__ W1r, const float* __restrict__ b1r,
    const float* __restrict__ att1,
    const float* __restrict__ W2l, const float* __restrict__ W2r,
    const float* __restrict__ b2l, const float* __restrict__ b2r,
    const float* __restrict__ att2,
    const int* __restrict__ ei,
    unsigned* __restrict__ xl1p, unsigned* __restrict__ xr1p,
    float* __restrict__ dotl1, float* __restrict__ dotr1,
    u16* __restrict__ Wtb, float* __restrict__ w2a,
    int* __restrict__ hist){
  const int bid = blockIdx.x;
  if(bid < LIN1_BLKS){
    const int lane = threadIdx.x & 63;
    const int n = bid*4 + (threadIdx.x >> 6);
    const float x0 = x[n*3], x1 = x[n*3+1], x2 = x[n*3+2];
    const int c0 = lane, c1 = lane + 64;
    const float la = x0*W1l[c0] + x1*W1l[HID+c0] + x2*W1l[2*HID+c0] + b1l[c0];
    const float lb = x0*W1l[c1] + x1*W1l[HID+c1] + x2*W1l[2*HID+c1] + b1l[c1];
    const float ra = x0*W1r[c0] + x1*W1r[HID+c0] + x2*W1r[2*HID+c0] + b1r[c0];
    const float rb = x0*W1r[c1] + x1*W1r[HID+c1] + x2*W1r[2*HID+c1] + b1r[c1];
    const float aa = att1[c0], ab = att1[c1];
    const float dl = wave_sum(la*aa + lb*ab);
    const float dr = wave_sum(ra*aa + rb*ab);
    if(lane == 0){ dotl1[n] = 0.6f*dl; dotr1[n] = 0.6f*dr; }
    xl1p[n*64+lane] = pack2(la, lb);
    xr1p[n*64+lane] = pack2(ra, rb);
  } else if(bid < LIN1_BLKS + WPREP_BLKS){
    const int idx = (bid - LIN1_BLKS)*256 + threadIdx.x;
    const int n = idx >> 7, k = idx & 127;
    const float v = (n < ENC) ? W2l[k*ENC + n] : W2r[k*ENC + (n-ENC)];
    Wtb[idx] = (u16)bf16rtne(v);
  } else if(bid < LIN1_BLKS + WPREP_BLKS + HIST_BLKS){
    const int i = (bid - LIN1_BLKS - WPREP_BLKS)*256 + threadIdx.x;
    const int dst = (i < N_EDGES) ? ei[N_EDGES + i] : (i - N_EDGES);
    atomicAdd(&hist[dst], 1);
  } else {
    // w2a[idx]: idx<128 -> W2l@att2 row k; idx<256 -> W2r@att2; 256/257 -> att2.b2l / att2.b2r
    const int idx = bid - (LIN1_BLKS + WPREP_BLKS + HIST_BLKS);
    const float* src = (idx < 128) ? (W2l + (size_t)idx*ENC)
                     : (idx < 256) ? (W2r + (size_t)(idx-128)*ENC)
                     : (idx == 256) ? b2l : b2r;
    float partial = 0.f;
    for(int c = threadIdx.x; c < ENC; c += 256) partial += src[c]*att2[c];
    partial = wave_sum(partial);
    __shared__ float red4[4];
    if((threadIdx.x & 63) == 0) red4[threadIdx.x >> 6] = partial;
    __syncthreads();
    if(threadIdx.x == 0) w2a[idx] = red4[0]+red4[1]+red4[2]+red4[3];
  }
}

// ---- single-block exclusive scan over N=16384 (1024 thr x 16 items) ----
__global__ __launch_bounds__(1024) void scan_kernel(
    const int* __restrict__ hist, int* __restrict__ rowstart){
  __shared__ int sums[1024];
  const int t = threadIdx.x;
  const int base = t*16;
  int loc[16];
  int s = 0;
  #pragma unroll
  for(int i=0;i<16;i++){ loc[i] = s; s += hist[base+i]; }
  sums[t] = s;
  __syncthreads();
  for(int off=1; off<1024; off<<=1){
    int v = 0;
    if(t >= off) v = sums[t-off];
    __syncthreads();
    if(t >= off) sums[t] += v;
    __syncthreads();
  }
  const int prev = (t==0) ? 0 : sums[t-1];
  #pragma unroll
  for(int i=0;i<16;i++) rowstart[base+i] = prev + loc[i];
  if(t == 1023) rowstart[N_NODES] = EP;
}

// ---- CSR build: scatter src ids into dst-sorted order ----
__global__ __launch_bounds__(256) void scatter_kernel(
    const int* __restrict__ ei, const int* __restrict__ rowstart,
    int* __restrict__ cursor, int* __restrict__ ssrc){
  const int i = blockIdx.x*256 + threadIdx.x;        // exactly EP threads
  const int src = (i < N_EDGES) ? ei[i]           : (i - N_EDGES);
  const int dst = (i < N_EDGES) ? ei[N_EDGES + i] : (i - N_EDGES);
  const int pos = rowstart[dst] + atomicAdd(&cursor[dst], 1);
  ssrc[pos] = src;
}

// ---- GAT layer 1 (abs-decomposed scores), emits h1b/h1p + layer-2 node dots ----
__global__ __launch_bounds__(256) void node1_kernel(
    const unsigned* __restrict__ xl1p, const unsigned* __restrict__ xr1p,
    const float* __restrict__ att1,
    const float* __restrict__ dotl1, const float* __restrict__ dotr1,
    const float* __restrict__ bias1,
    const float* __restrict__ g1, const float* __restrict__ b1,
    const float* __restrict__ w2a,
    const int* __restrict__ rowstart, const int* __restrict__ ssrc,
    u16* __restrict__ h1b, unsigned* __restrict__ h1p,
    float* __restrict__ dotl2, float* __restrict__ dotr2){
  const int lane = threadIdx.x & 63;
  const int n = blockIdx.x*4 + (threadIdx.x >> 6);
  const unsigned xru = xr1p[n*64 + lane];
  const float xra = plo(xru), xrb = phi(xru);
  const float sa = 0.4f*att1[lane], sb = 0.4f*att1[lane+64];
  const float ebase = dotr1[n];
  float acc0 = 0.f, acc1 = 0.f, denom = 0.f;
  int p = rowstart[n];
  const int p1 = rowstart[n+1];
  for(; p+1 < p1; p += 2){
    const int s0 = ssrc[p], s1 = ssrc[p+1];
    const unsigned u0 = xl1p[s0*64 + lane];
    const unsigned u1 = xl1p[s1*64 + lane];
    const float dl0 = dotl1[s0], dl1 = dotl1[s1];
    const float a0 = plo(u0), b0 = phi(u0);
    const float a1 = plo(u1), b1v = phi(u1);
    float q0 = fmaf(sa, __builtin_fabsf(a0+xra), sb*__builtin_fabsf(b0+xrb));
    float q1 = fmaf(sa, __builtin_fabsf(a1+xra), sb*__builtin_fabsf(b1v+xrb));
    #pragma unroll
    for(int m=32;m>=1;m>>=1){
      q0 += __shfl_xor(q0, m, 64);
      q1 += __shfl_xor(q1, m, 64);
    }
    const float w0 = __expf(q0 + dl0 + ebase), w1 = __expf(q1 + dl1 + ebase);
    denom += w0 + w1;
    acc0 += w0*a0 + w1*a1;
    acc1 += w0*b0 + w1*b1v;
  }
  if(p < p1){
    const int s0 = ssrc[p];
    const unsigned u0 = xl1p[s0*64 + lane];
    const float a0 = plo(u0), b0 = phi(u0);
    const float q = wave_sum(fmaf(sa, __builtin_fabsf(a0+xra), sb*__builtin_fabsf(b0+xrb)));
    const float w0 = __expf(q + dotl1[s0] + ebase);
    denom += w0; acc0 += w0*a0; acc1 += w0*b0;
  }
  const float inv = 1.f/denom;
  const float y0 = acc0*inv + bias1[lane];
  const float y1 = acc1*inv + bias1[lane+64];
  const float mu  = wave_sum(y0+y1) * (1.f/HID);
  const float d0 = y0-mu, d1 = y1-mu;
  const float var = wave_sum(d0*d0 + d1*d1) * (1.f/HID);
  const float r = rsqrtf(var + EPSV);
  float z0 = d0*r*g1[lane] + b1[lane];
  float z1 = d1*r*g1[lane+64] + b1[lane+64];
  z0 = z0 > 0.f ? z0 : expm1f(z0);        // ELU(alpha=1)
  z1 = z1 > 0.f ? z1 : expm1f(z1);
  h1b[n*HID+lane]    = (u16)bf16rtne(z0);
  h1b[n*HID+lane+64] = (u16)bf16rtne(z1);
  h1p[n*64+lane]     = pack2(z0, z1);
  // layer-2 per-node linear score terms: 0.6*(att2 . xl2/xr2[n])
  float dl2 = z0*w2a[lane]     + z1*w2a[lane+64];
  float dr2 = z0*w2a[128+lane] + z1*w2a[128+lane+64];
  #pragma unroll
  for(int m=32;m>=1;m>>=1){
    dl2 += __shfl_xor(dl2, m, 64);
    dr2 += __shfl_xor(dr2, m, 64);
  }
  if(lane == 0){
    dotl2[n] = 0.6f*(dl2 + w2a[256]);
    dotr2[n] = 0.6f*(dr2 + w2a[257]);
  }
}

// ---- MFMA GEMM: l-half -> fp8 xl8[N][768]B (scores only), r-half -> bf16 xr2b ----
#define LBM 128
#define LBN 128
__global__ __launch_bounds__(256) void mfma_lin2_kernel(
    const u16* __restrict__ h1b, const u16* __restrict__ Wtb,
    const float* __restrict__ b2l, const float* __restrict__ b2r,
    u8* __restrict__ xl8, u16* __restrict__ xr2u){
  __shared__ __align__(16) u16 Cs[LBM*128];   // 32 KB bounce, swizzled rows
  const int t = threadIdx.x;
  const int mb = blockIdx.x * LBM;
  const int nb = blockIdx.y * LBN;
  const int w = t >> 6, lane = t & 63;
  const int l15 = lane & 15, g = lane >> 4;
  const int ar0 = mb + w*32 + l15, ar1 = ar0 + 16;
  bf16x8 a0[4], a1[4];
  #pragma unroll
  for(int ks=0;ks<4;ks++){
    a0[ks] = *(const bf16x8*)(h1b + (size_t)ar0*128 + ks*32 + g*8);
    a1[ks] = *(const bf16x8*)(h1b + (size_t)ar1*128 + ks*32 + g*8);
  }
  f32x4 acc0[8], acc1[8];
  #pragma unroll
  for(int j=0;j<8;j++){ acc0[j]=(f32x4){0,0,0,0}; acc1[j]=(f32x4){0,0,0,0}; }
  #pragma unroll
  for(int j=0;j<8;j++){
    const int brn = nb + j*16 + l15;
    #pragma unroll
    for(int ks=0;ks<4;ks++){
      const bf16x8 b = *(const bf16x8*)(Wtb + (size_t)brn*128 + ks*32 + g*8);
      acc0[j] = __builtin_amdgcn_mfma_f32_16x16x32_bf16(a0[ks], b, acc0[j], 0,0,0);
      acc1[j] = __builtin_amdgcn_mfma_f32_16x16x32_bf16(a1[ks], b, acc1[j], 0,0,0);
    }
  }
  if(nb < ENC){
    // fp8 epilogue (score table): rows of 128 bytes in this block
    u8* Cs8 = (u8*)Cs;
    float biasj[8];
    #pragma unroll
    for(int j=0;j<8;j++) biasj[j] = b2l[nb + j*16 + l15];
    #pragma unroll
    for(int j=0;j<8;j++){
      const int col = j*16 + l15;               // byte offset within 128B slice
      #pragma unroll
      for(int r4=0;r4<4;r4++){
        const int row0 = w*32 + g*4 + r4;
        Cs8[row0*128 + (col ^ ((row0&7)<<4))] = f2fp8(acc0[j][r4] + biasj[j]);
        const int row1 = row0 + 16;
        Cs8[row1*128 + (col ^ ((row1&7)<<4))] = f2fp8(acc1[j][r4] + biasj[j]);
      }
    }
    __syncthreads();
    #pragma unroll
    for(int idx=t; idx<LBM*8; idx+=256){
      const int row = idx >> 3, ch = idx & 7;
      const uint4 v = *(const uint4*)(Cs8 + row*128 + ((ch*16) ^ ((row&7)<<4)));
      *(uint4*)(xl8 + (size_t)(mb+row)*ENC + nb + ch*16) = v;
    }
  } else {
    const float* bsrc = b2r + (nb - ENC);
    float biasj[8];
    #pragma unroll
    for(int j=0;j<8;j++) biasj[j] = bsrc[j*16 + l15];
    #pragma unroll
    for(int j=0;j<8;j++){
      const int coll = j*16 + l15;              // C/D: col = lane&15 (verified)
      #pragma unroll
      for(int r4=0;r4<4;r4++){
        const int row0 = w*32 + g*4 + r4;       // C/D: row = (lane>>4)*4+reg
        *(u16*)((char*)Cs + row0*256 + ((coll*2) ^ ((row0&7)<<4))) =
            (u16)bf16rtne(acc0[j][r4] + biasj[j]);
        const int row1 = row0 + 16;
        *(u16*)((char*)Cs + row1*256 + ((coll*2) ^ ((row1&7)<<4))) =
            (u16)bf16rtne(acc1[j][r4] + biasj[j]);
      }
    }
    __syncthreads();
    u16* dst0 = xr2u + (nb - ENC);
    const int rr = t >> 4, cc = t & 15;
    #pragma unroll
    for(int it=0; it<8; ++it){
      const int row = it*16 + rr;
      const uint4 v = *(const uint4*)((const char*)Cs + row*256 + ((cc*16) ^ ((row&7)<<4)));
      *(uint4*)(dst0 + (size_t)(mb+row)*ENC + cc*8) = v;
    }
  }
}

// ---- GAT layer 2: fp8 score gather + abs-decomposition; aggregate bf16 h1p ----
__global__ __launch_bounds__(256) void node2b_kernel(
    const u8* __restrict__ xl8, const unsigned* __restrict__ xr2b,
    const float* __restrict__ att2,
    const float* __restrict__ dotl2, const float* __restrict__ dotr2,
    const unsigned* __restrict__ h1p,
    const int* __restrict__ rowstart, const int* __restrict__ ssrc,
    u16* __restrict__ aggb){
  const int lane = threadIdx.x & 63;
  const int n = blockIdx.x*4 + (threadIdx.x >> 6);
  const uint2* xrrow = (const uint2*)(xr2b + (size_t)n*ENCP);
  float xr[12], sg[12];
  #pragma unroll
  for(int k=0;k<3;k++){
    const uint2 u = xrrow[lane + 64*k];
    xr[4*k]   = plo(u.x); xr[4*k+1] = phi(u.x);
    xr[4*k+2] = plo(u.y); xr[4*k+3] = phi(u.y);
    const int cb = 4*(lane + 64*k);
    sg[4*k]   = 0.4f*att2[cb];   sg[4*k+1] = 0.4f*att2[cb+1];
    sg[4*k+2] = 0.4f*att2[cb+2]; sg[4*k+3] = 0.4f*att2[cb+3];
  }
  const float ebase = dotr2[n];
  float denom = 0.f, acc0 = 0.f, acc1 = 0.f;
  int p = rowstart[n];
  const int p1 = rowstart[n+1];
  for(; p+1 < p1; p += 2){
    const int s0 = ssrc[p], s1 = ssrc[p+1];
    const unsigned* r0 = (const unsigned*)(xl8 + (size_t)s0*ENC);
    const unsigned* r1 = (const unsigned*)(xl8 + (size_t)s1*ENC);
    unsigned v0[3], v1[3];
    #pragma unroll
    for(int k=0;k<3;k++){ v0[k] = r0[lane + 64*k]; v1[k] = r1[lane + 64*k]; }
    const float dl0 = dotl2[s0], dl1 = dotl2[s1];
    const unsigned hu0 = h1p[s0*64 + lane];
    const unsigned hu1 = h1p[s1*64 + lane];
    float q0 = 0.f, q1 = 0.f;
    #pragma unroll
    for(int k=0;k<3;k++){
      const v2f f01 = __builtin_amdgcn_cvt_pk_f32_fp8(v0[k], false);
      const v2f f23 = __builtin_amdgcn_cvt_pk_f32_fp8(v0[k], true);
      q0 = fmaf(sg[4*k],   __builtin_fabsf(f01.x+xr[4*k]),   q0);
      q0 = fmaf(sg[4*k+1], __builtin_fabsf(f01.y+xr[4*k+1]), q0);
      q0 = fmaf(sg[4*k+2], __builtin_fabsf(f23.x+xr[4*k+2]), q0);
      q0 = fmaf(sg[4*k+3], __builtin_fabsf(f23.y+xr[4*k+3]), q0);
      const v2f g01 = __builtin_amdgcn_cvt_pk_f32_fp8(v1[k], false);
      const v2f g23 = __builtin_amdgcn_cvt_pk_f32_fp8(v1[k], true);
      q1 = fmaf(sg[4*k],   __builtin_fabsf(g01.x+xr[4*k]),   q1);
      q1 = fmaf(sg[4*k+1], __builtin_fabsf(g01.y+xr[4*k+1]), q1);
      q1 = fmaf(sg[4*k+2], __builtin_fabsf(g23.x+xr[4*k+2]), q1);
      q1 = fmaf(sg[4*k+3], __builtin_fabsf(g23.y+xr[4*k+3]), q1);
    }
    #pragma unroll
    for(int m=32;m>=1;m>>=1){
      q0 += __shfl_xor(q0, m, 64);
      q1 += __shfl_xor(q1, m, 64);
    }
    const float w0 = __expf(q0 + dl0 + ebase), w1 = __expf(q1 + dl1 + ebase);
    denom += w0 + w1;
    acc0 += w0*plo(hu0) + w1*plo(hu1);
    acc1 += w0*phi(hu0) + w1*phi(hu1);
  }
  if(p < p1){
    const int s0 = ssrc[p];
    const unsigned* r0 = (const unsigned*)(xl8 + (size_t)s0*ENC);
    float q0 = 0.f;
    #pragma unroll
    for(int k=0;k<3;k++){
      const unsigned v = r0[lane + 64*k];
      const v2f f01 = __builtin_amdgcn_cvt_pk_f32_fp8(v, false);
      const v2f f23 = __builtin_amdgcn_cvt_pk_f32_fp8(v, true);
      q0 = fmaf(sg[4*k],   __builtin_fabsf(f01.x+xr[4*k]),   q0);
      q0 = fmaf(sg[4*k+1], __builtin_fabsf(f01.y+xr[4*k+1]), q0);
      q0 = fmaf(sg[4*k+2], __builtin_fabsf(f23.x+xr[4*k+2]), q0);
      q0 = fmaf(sg[4*k+3], __builtin_fabsf(f23.y+xr[4*k+3]), q0);
    }
    const unsigned hu0 = h1p[s0*64 + lane];
    const float w0 = __expf(wave_sum(q0) + dotl2[s0] + ebase);
    denom += w0; acc0 += w0*plo(hu0); acc1 += w0*phi(hu0);
  }
  const float inv = 1.f/denom;
  aggb[n*HID+lane]    = (u16)bf16rtne(acc0*inv);
  aggb[n*HID+lane+64] = (u16)bf16rtne(acc1*inv);
}

// ---- final fused: out = LN( aggb@W2l + b2l + bias2 + x@Wfc + bfc ) ----
#define YSTR 770
__global__ __launch_bounds__(256) void gemm3_mfma_kernel(
    const u16* __restrict__ aggb, const u16* __restrict__ Wtb,
    const float* __restrict__ b2l, const float* __restrict__ bias2,
    const float* __restrict__ x, const float* __restrict__ Wfc,
    const float* __restrict__ bfc,
    const float* __restrict__ gn, const float* __restrict__ bn,
    float* __restrict__ out){
  __shared__ u16 Ys[64*YSTR];
  __shared__ float cbs[ENC];
  __shared__ float wfs[3][ENC];
  __shared__ float mus[64], rss[64];
  const int t = threadIdx.x;
  const int mb = blockIdx.x * 64;
  for(int c=t; c<ENC; c+=256){
    cbs[c] = b2l[c] + bias2[c] + bfc[c];
    wfs[0][c] = Wfc[c]; wfs[1][c] = Wfc[ENC+c]; wfs[2][c] = Wfc[2*ENC+c];
  }
  const int w = t >> 6, lane = t & 63;
  const int l15 = lane & 15, g = lane >> 4;
  const int ar = mb + w*16 + l15;
  bf16x8 a[4];
  #pragma unroll
  for(int ks=0;ks<4;ks++)
    a[ks] = *(const bf16x8*)(aggb + (size_t)ar*128 + ks*32 + g*8);
  float xv0[4], xv1[4], xv2[4];
  #pragma unroll
  for(int r4=0;r4<4;r4++){
    const int rrow = mb + w*16 + g*4 + r4;
    xv0[r4] = x[rrow*3]; xv1[r4] = x[rrow*3+1]; xv2[r4] = x[rrow*3+2];
  }
  float rs[4] = {0,0,0,0}, rq[4] = {0,0,0,0};
  __syncthreads();
  #pragma unroll
  for(int sub=0; sub<6; ++sub){
    const int nb = sub*128;
    f32x4 acc[8];
    #pragma unroll
    for(int j=0;j<8;j++) acc[j]=(f32x4){0,0,0,0};
    #pragma unroll
    for(int j=0;j<8;j++){
      const int brn = nb + j*16 + l15;
      #pragma unroll
      for(int ks=0;ks<4;ks++){
        const bf16x8 b = *(const bf16x8*)(Wtb + (size_t)brn*128 + ks*32 + g*8);
        acc[j] = __builtin_amdgcn_mfma_f32_16x16x32_bf16(a[ks], b, acc[j], 0,0,0);
      }
    }
    #pragma unroll
    for(int j=0;j<8;j++){
      const int col = nb + j*16 + l15;
      const float cb = cbs[col];
      const float w0 = wfs[0][col], w1 = wfs[1][col], w2 = wfs[2][col];
      #pragma unroll
      for(int r4=0;r4<4;r4++){
        const int lrow = w*16 + g*4 + r4;
        const float y = acc[j][r4] + cb + xv0[r4]*w0 + xv1[r4]*w1 + xv2[r4]*w2;
        rs[r4] += y; rq[r4] += y*y;
        Ys[lrow*YSTR + col] = (u16)bf16rtne(y);
      }
    }
  }
  #pragma unroll
  for(int m=8;m>=1;m>>=1){
    #pragma unroll
    for(int r4=0;r4<4;r4++){
      rs[r4] += __shfl_xor(rs[r4], m, 64);
      rq[r4] += __shfl_xor(rq[r4], m, 64);
    }
  }
  if(l15 == 0){
    #pragma unroll
    for(int r4=0;r4<4;r4++){
      const int lrow = w*16 + g*4 + r4;
      const float mu = rs[r4] * (1.f/ENC);
      const float var = rq[r4] * (1.f/ENC) - mu*mu;
      mus[lrow] = mu;
      rss[lrow] = rsqrtf(var + EPSV);
    }
  }
  __syncthreads();
  float gv[12], bv[12];
  #pragma unroll
  for(int j2=0;j2<12;j2++){ gv[j2] = gn[lane + j2*64]; bv[j2] = bn[lane + j2*64]; }
  for(int r=0; r<16; ++r){
    const int lrow = w*16 + r;
    const float mu = mus[lrow], rstd = rss[lrow];
    float* orow = out + (size_t)(mb+lrow)*ENC;
    #pragma unroll
    for(int j2=0;j2<12;j2++){
      const float y = bf2f(Ys[lrow*YSTR + lane + j2*64]);
      orow[lane + j2*64] = (y - mu)*rstd*gv[j2] + bv[j2];
    }
  }
}

extern "C" void kernel_launch(void* const* d_in, const int* in_sizes, int n_in,
                              void* d_out, int out_size, void* d_ws, size_t ws_size,
                              hipStream_t stream) {
  const float* x    = (const float*)d_in[0];
  const int*   ei   = (const int*)  d_in[1];
  const float* Wfc  = (const float*)d_in[2];
  const float* bfc  = (const float*)d_in[3];
  const float* W1l  = (const float*)d_in[4];
  const float* b1l  = (const float*)d_in[5];
  const float* W1r  = (const float*)d_in[6];
  const float* b1r  = (const float*)d_in[7];
  const float* att1 = (const float*)d_in[8];
  const float* bias1= (const float*)d_in[9];
  const float* g1   = (const float*)d_in[10];
  const float* bb1  = (const float*)d_in[11];
  const float* W2l  = (const float*)d_in[12];
  const float* b2l  = (const float*)d_in[13];
  const float* W2r  = (const float*)d_in[14];
  const float* b2r  = (const float*)d_in[15];
  const float* att2 = (const float*)d_in[16];
  const float* bias2= (const float*)d_in[17];
  const float* gn   = (const float*)d_in[18];
  const float* bn   = (const float*)d_in[19];
  float* out = (float*)d_out;

  char* w = (char*)d_ws;
  auto alloc = [&](size_t bytes){ void* p = (void*)w; w += (bytes + 255) & ~(size_t)255; return p; };
  int*      hist     = (int*)     alloc((size_t)N_NODES*4);   // contiguous with cursor
  int*      cursor   = (int*)     alloc((size_t)N_NODES*4);
  int*      rowstart = (int*)     alloc((size_t)(N_NODES+1)*4);
  int*      ssrc     = (int*)     alloc((size_t)EP*4);
  unsigned* xl1p     = (unsigned*)alloc((size_t)N_NODES*64*4);
  unsigned* xr1p     = (unsigned*)alloc((size_t)N_NODES*64*4);
  float*    dotl1    = (float*)   alloc((size_t)N_NODES*4);
  float*    dotr1    = (float*)   alloc((size_t)N_NODES*4);
  float*    dotl2    = (float*)   alloc((size_t)N_NODES*4);
  float*    dotr2    = (float*)   alloc((size_t)N_NODES*4);
  u16*      h1b      = (u16*)     alloc((size_t)N_NODES*HID*2);
  unsigned* h1p      = (unsigned*)alloc((size_t)N_NODES*64*4);
  u16*      aggb     = (u16*)     alloc((size_t)N_NODES*HID*2);
  u8*       xl8      = (u8*)      alloc((size_t)N_NODES*ENC);
  unsigned* xr2b     = (unsigned*)alloc((size_t)N_NODES*ENCP*4);
  u16*      Wtb      = (u16*)     alloc((size_t)2*ENC*HID*2);
  float*    w2a      = (float*)   alloc((size_t)W2A_BLKS*4);

  hipMemsetAsync(hist, 0, (size_t)N_NODES*8, stream);   // hist + cursor

  prep_kernel<<<LIN1_BLKS+WPREP_BLKS+HIST_BLKS+W2A_BLKS, 256, 0, stream>>>(
      x, W1l, b1l, W1r, b1r, att1, W2l, W2r, b2l, b2r, att2, ei,
      xl1p, xr1p, dotl1, dotr1, Wtb, w2a, hist);
  scan_kernel<<<1, 1024, 0, stream>>>(hist, rowstart);
  scatter_kernel<<<EP/256, 256, 0, stream>>>(ei, rowstart, cursor, ssrc);
  node1_kernel<<<N_NODES/4, 256, 0, stream>>>(xl1p, xr1p, att1, dotl1, dotr1,
                                              bias1, g1, bb1, w2a,
                                              rowstart, ssrc, h1b, h1p, dotl2, dotr2);
  mfma_lin2_kernel<<<dim3(N_NODES/LBM, 2*ENC/LBN), 256, 0, stream>>>(
      h1b, Wtb, b2l, b2r, xl8, (u16*)xr2b);
  node2b_kernel<<<N_NODES/4, 256, 0, stream>>>(xl8, xr2b, att2, dotl2, dotr2,
                                               h1p, rowstart, ssrc, aggb);
  gemm3_mfma_kernel<<<N_NODES/64, 256, 0, stream>>>(aggb, Wtb, b2l, bias2,
                                                    x, Wfc, bfc, gn, bn, out);
}